// Round 1
// baseline (7145.260 us; speedup 1.0000x reference)
//
#include <hip/hip_runtime.h>
#include <math.h>

// FAENet forward, fp32 baseline.
// ws layout (floats): e[E*128] | hd[N*128] | agg[N*128] | h[N*256] | stats[256] | ab[256]
// t1 (N*256) aliases hd+agg (dead before hd first written); h1 (N*128) aliases hd
// (written after hd's last read). Total ~512 MB.

#define EPS_GN 1e-5f

__device__ __forceinline__ float silu_f(float x) {
    return x / (1.0f + __expf(-x));
}

enum { PRO_NONE = 0, PRO_EMB = 1, PRO_EDGE = 2, PRO_AFF = 3 };
enum { EPI_STORE = 0, EPI_SCATTER = 1, EPI_RESID = 2 };

// C[M x NFTOT] = epi( silu-free acc = A[M x K] @ W[NFTOT x K]^T + bias )
// Tiles: block = 128 rows x 128 cols, 256 threads, 8x8 per thread (4+4 split),
// BK = 32. A staged transposed in LDS (stride 132), B likewise.
template<int K, int PRO, int EPI>
__global__ __launch_bounds__(256)
void gemm_fused(const float* __restrict__ A, const float* __restrict__ W,
                const float* __restrict__ bias, float* __restrict__ C,
                int M, int NFTOT,
                const int* __restrict__ iz, const int* __restrict__ itag,
                const float* __restrict__ p0, const float* __restrict__ p1,
                const float* __restrict__ p2, const float* __restrict__ p3,
                const float* __restrict__ p4, const float* __restrict__ p5,
                const int* __restrict__ esrc, const int* __restrict__ edst,
                const float* __restrict__ hd, float* __restrict__ agg)
{
    __shared__ __align__(16) float As[32 * 132];
    __shared__ __align__(16) float Bs[32 * 132];

    const int tid = threadIdx.x;
    const int m0 = blockIdx.x * 128;
    const int n0 = blockIdx.y * 128;
    const int tx = tid & 15;   // feature dir
    const int ty = tid >> 4;   // row dir
    const int ar = tid >> 3;        // 0..31 (staging row / b-col)
    const int ac = (tid & 7) << 2;  // 0..28 (staging k, x4)

    float acc[8][8];
#pragma unroll
    for (int i = 0; i < 8; ++i)
#pragma unroll
        for (int j = 0; j < 8; ++j) acc[i][j] = 0.0f;

    for (int k0 = 0; k0 < K; k0 += 32) {
        // ---- stage A tile (transposed: As[k][m]) ----
#pragma unroll
        for (int i = 0; i < 4; ++i) {
            int row = m0 + ar + 32 * i;
            int rc = row < M ? row : M - 1;
            float4 v;
            if (PRO == PRO_NONE) {
                v = *(const float4*)(A + (size_t)rc * K + k0 + ac);
            } else if (PRO == PRO_AFF) {
                float4 t = *(const float4*)(A + (size_t)rc * K + k0 + ac);
                float4 a4 = *(const float4*)(p0 + k0 + ac);
                float4 b4 = *(const float4*)(p0 + 128 + k0 + ac);
                v.x = silu_f(a4.x * t.x + b4.x);
                v.y = silu_f(a4.y * t.y + b4.y);
                v.z = silu_f(a4.z * t.z + b4.z);
                v.w = silu_f(a4.w * t.w + b4.w);
            } else if (PRO == PRO_EMB) {
                int kg = k0 + ac;
                if (kg < 224) v = *(const float4*)(p0 + (size_t)iz[rc] * 224 + kg);
                else          v = *(const float4*)(p1 + (size_t)itag[rc] * 32 + (kg - 224));
            } else { // PRO_EDGE: compute silu(concat(relpos@W1^T+b1, attr@W12^T+b12))
                int kg = k0 + ac;
                if (kg < 64) {
                    float x = p0[(size_t)rc * 3 + 0];
                    float y = p0[(size_t)rc * 3 + 1];
                    float z2 = p0[(size_t)rc * 3 + 2];
#pragma unroll
                    for (int c = 0; c < 4; ++c) {
                        int kk = kg + c;
                        float s = p2[kk * 3 + 0] * x + p2[kk * 3 + 1] * y +
                                  p2[kk * 3 + 2] * z2 + p3[kk];
                        ((float*)&v)[c] = silu_f(s);
                    }
                } else {
                    int g = kg - 64;
                    float s0 = p5[g + 0], s1 = p5[g + 1], s2v = p5[g + 2], s3 = p5[g + 3];
                    const float* ea = p1 + (size_t)rc * 50;
                    const float* w0 = p4 + (size_t)g * 50;
                    for (int j = 0; j < 50; ++j) {
                        float ev = ea[j];
                        s0  = fmaf(ev, w0[j],        s0);
                        s1  = fmaf(ev, w0[50 + j],   s1);
                        s2v = fmaf(ev, w0[100 + j],  s2v);
                        s3  = fmaf(ev, w0[150 + j],  s3);
                    }
                    v = make_float4(silu_f(s0), silu_f(s1), silu_f(s2v), silu_f(s3));
                }
            }
            As[(ac + 0) * 132 + ar + 32 * i] = v.x;
            As[(ac + 1) * 132 + ar + 32 * i] = v.y;
            As[(ac + 2) * 132 + ar + 32 * i] = v.z;
            As[(ac + 3) * 132 + ar + 32 * i] = v.w;
        }
        // ---- stage B tile (W[f][k] -> Bs[k][f]) ----
#pragma unroll
        for (int i = 0; i < 4; ++i) {
            int c = ar + 32 * i;
            float4 w = *(const float4*)(W + (size_t)(n0 + c) * K + k0 + ac);
            Bs[(ac + 0) * 132 + c] = w.x;
            Bs[(ac + 1) * 132 + c] = w.y;
            Bs[(ac + 2) * 132 + c] = w.z;
            Bs[(ac + 3) * 132 + c] = w.w;
        }
        __syncthreads();
#pragma unroll
        for (int k = 0; k < 32; ++k) {
            float4 a0 = *(const float4*)(As + k * 132 + ty * 4);
            float4 a1 = *(const float4*)(As + k * 132 + 64 + ty * 4);
            float4 b0 = *(const float4*)(Bs + k * 132 + tx * 4);
            float4 b1 = *(const float4*)(Bs + k * 132 + 64 + tx * 4);
            float av[8] = {a0.x, a0.y, a0.z, a0.w, a1.x, a1.y, a1.z, a1.w};
            float bv[8] = {b0.x, b0.y, b0.z, b0.w, b1.x, b1.y, b1.z, b1.w};
#pragma unroll
            for (int i = 0; i < 8; ++i)
#pragma unroll
                for (int j = 0; j < 8; ++j)
                    acc[i][j] = fmaf(av[i], bv[j], acc[i][j]);
        }
        __syncthreads();
    }

    // ---- epilogue ----
    float4 bi0 = *(const float4*)(bias + n0 + tx * 4);
    float4 bi1 = *(const float4*)(bias + n0 + 64 + tx * 4);
    float bb[8] = {bi0.x, bi0.y, bi0.z, bi0.w, bi1.x, bi1.y, bi1.z, bi1.w};

#pragma unroll
    for (int i = 0; i < 8; ++i) {
        int rloc = (i < 4) ? (ty * 4 + i) : (64 + ty * 4 + i - 4);
        int r = m0 + rloc;
        if (r >= M) continue;
        float o[8];
#pragma unroll
        for (int j = 0; j < 8; ++j) o[j] = silu_f(acc[i][j] + bb[j]);
        if (EPI == EPI_STORE) {
            *(float4*)(C + (size_t)r * NFTOT + n0 + tx * 4) =
                make_float4(o[0], o[1], o[2], o[3]);
            *(float4*)(C + (size_t)r * NFTOT + n0 + 64 + tx * 4) =
                make_float4(o[4], o[5], o[6], o[7]);
        } else if (EPI == EPI_RESID) {
            float* c0 = C + (size_t)r * NFTOT + n0 + tx * 4;
            float* c1 = C + (size_t)r * NFTOT + n0 + 64 + tx * 4;
            float4 h0 = *(float4*)c0, h1v = *(float4*)c1;
            h0.x += o[0]; h0.y += o[1]; h0.z += o[2]; h0.w += o[3];
            h1v.x += o[4]; h1v.y += o[5]; h1v.z += o[6]; h1v.w += o[7];
            *(float4*)c0 = h0;
            *(float4*)c1 = h1v;
        } else { // EPI_SCATTER: msg = silu(e@W^T+b) * hd[src]; agg[dst] += msg
            int s = esrc[r], d = edst[r];
            const float* hr = hd + (size_t)s * 128;
            float* arow = agg + (size_t)d * 128;
            float4 h0 = *(const float4*)(hr + tx * 4);
            float4 h1v = *(const float4*)(hr + 64 + tx * 4);
            atomicAdd(arow + tx * 4 + 0, o[0] * h0.x);
            atomicAdd(arow + tx * 4 + 1, o[1] * h0.y);
            atomicAdd(arow + tx * 4 + 2, o[2] * h0.z);
            atomicAdd(arow + tx * 4 + 3, o[3] * h0.w);
            atomicAdd(arow + 64 + tx * 4 + 0, o[4] * h1v.x);
            atomicAdd(arow + 64 + tx * 4 + 1, o[5] * h1v.y);
            atomicAdd(arow + 64 + tx * 4 + 2, o[6] * h1v.z);
            atomicAdd(arow + 64 + tx * 4 + 3, o[7] * h1v.w);
        }
    }
}

// per-feature sum and sumsq of agg[N][128] -> sums[0:128]=sum, sums[128:256]=sumsq
__global__ __launch_bounds__(256)
void gn_stats(const float* __restrict__ agg, float* __restrict__ sums, int N)
{
    __shared__ float red[512];
    int f = threadIdx.x & 127;
    int sub = threadIdx.x >> 7; // 0/1
    float s = 0.f, s2 = 0.f;
    for (int r = blockIdx.x * 2 + sub; r < N; r += gridDim.x * 2) {
        float v = agg[(size_t)r * 128 + f];
        s += v;
        s2 += v * v;
    }
    red[threadIdx.x] = s;
    red[256 + threadIdx.x] = s2;
    __syncthreads();
    if (sub == 0) {
        s = red[f] + red[128 + f];
        s2 = red[256 + f] + red[384 + f];
        atomicAdd(&sums[f], s);
        atomicAdd(&sums[128 + f], s2);
    }
}

// gn(x) = a*x + b with a = gn_w*rstd, b = gn_b - a*mean*ms
__global__ void gn_finalize(const float* __restrict__ sums,
                            const float* __restrict__ gnw, const float* __restrict__ gnb,
                            const float* __restrict__ gnms, float* __restrict__ ab,
                            float invN)
{
    int f = threadIdx.x; // 128
    float mean = sums[f] * invN;
    float ex2 = sums[128 + f] * invN;
    float m2 = mean * gnms[f];
    float var = ex2 - 2.f * m2 * mean + m2 * m2;
    float rstd = 1.0f / sqrtf(var + EPS_GN);
    float a = gnw[f] * rstd;
    ab[f] = a;
    ab[128 + f] = gnb[f] - a * m2;
}

// node_e = h1 @ out2_w^T + b; out[batch[n]] += node_e   (wave per row)
__global__ __launch_bounds__(256)
void out_reduce(const float* __restrict__ h1, const float* __restrict__ w2,
                const float* __restrict__ b2, const int* __restrict__ batch,
                float* __restrict__ out, int N)
{
    int lane = threadIdx.x & 63;
    int wid = blockIdx.x * 4 + (threadIdx.x >> 6);
    int nw = gridDim.x * 4;
    float wa = w2[lane], wb = w2[64 + lane];
    float bb = b2[0];
    for (int r = wid; r < N; r += nw) {
        float v = h1[(size_t)r * 128 + lane] * wa + h1[(size_t)r * 128 + 64 + lane] * wb;
#pragma unroll
        for (int off = 32; off > 0; off >>= 1) v += __shfl_down(v, off);
        if (lane == 0) atomicAdd(&out[batch[r]], v + bb);
    }
}

#define NULL_PRO (const int*)nullptr, (const int*)nullptr, (const float*)nullptr, \
                 (const float*)nullptr, (const float*)nullptr, (const float*)nullptr, \
                 (const float*)nullptr, (const float*)nullptr
#define NULL_EPI (const int*)nullptr, (const int*)nullptr, (const float*)nullptr, \
                 (float*)nullptr

extern "C" void kernel_launch(void* const* d_in, const int* in_sizes, int n_in,
                              void* d_out, int out_size, void* d_ws, size_t ws_size,
                              hipStream_t stream)
{
    const int*   z         = (const int*)d_in[0];
    const int*   tag       = (const int*)d_in[1];
    const float* rel_pos   = (const float*)d_in[2];
    const float* edge_attr = (const float*)d_in[3];
    const int*   eidx      = (const int*)d_in[4];
    const int*   batch     = (const int*)d_in[5];
    const float* le1w  = (const float*)d_in[6];
    const float* le1b  = (const float*)d_in[7];
    const float* le12w = (const float*)d_in[8];
    const float* le12b = (const float*)d_in[9];
    const float* le2w  = (const float*)d_in[10];
    const float* le2b  = (const float*)d_in[11];
    const float* embw  = (const float*)d_in[12];
    const float* tembw = (const float*)d_in[13];
    const float* linw  = (const float*)d_in[14];
    const float* linb  = (const float*)d_in[15];
    const float* lin2w = (const float*)d_in[16];
    const float* lin2b = (const float*)d_in[17];
    const float* geomw = (const float*)d_in[18];
    const float* geomb = (const float*)d_in[19];
    const float* downw = (const float*)d_in[20];
    const float* downb = (const float*)d_in[21];
    const float* upw   = (const float*)d_in[22];
    const float* upb   = (const float*)d_in[23];
    const float* gnw   = (const float*)d_in[24];
    const float* gnb   = (const float*)d_in[25];
    const float* gnms  = (const float*)d_in[26];
    const float* o1w   = (const float*)d_in[27];
    const float* o1b   = (const float*)d_in[28];
    const float* o2w   = (const float*)d_in[29];
    const float* o2b   = (const float*)d_in[30];

    const int N = in_sizes[0];
    const int E = in_sizes[2] / 3;
    const int* esrc = eidx;
    const int* edst = eidx + E;

    float* ws = (float*)d_ws;
    size_t off = 0;
    float* e   = ws + off; off += (size_t)E * 128;
    float* hd  = ws + off; off += (size_t)N * 128;
    float* agg = ws + off; off += (size_t)N * 128;
    float* h   = ws + off; off += (size_t)N * 256;
    float* stats = ws + off; off += 256;
    float* ab    = ws + off; off += 256;
    float* t1 = hd;  // alias: t1 (N*256) dead before hd/agg first written
    float* h1 = hd;  // alias: h1 (N*128) written after hd's last read

    const int mbE = (E + 127) / 128;
    const int mbN = (N + 127) / 128;
    dim3 blk(256);

    // 1) edge embedding: e = silu(silu(cat(rp@W1^T, ea@W12^T)) @ le2w^T + b)
    gemm_fused<128, PRO_EDGE, EPI_STORE><<<dim3(mbE, 1), blk, 0, stream>>>(
        nullptr, le2w, le2b, e, E, 128,
        (const int*)nullptr, (const int*)nullptr,
        rel_pos, edge_attr, le1w, le1b, le12w, le12b,
        NULL_EPI);

    // 2) node embedding: t1 = silu(cat(emb[z],temb[tag]) @ linw^T + b)
    gemm_fused<256, PRO_EMB, EPI_STORE><<<dim3(mbN, 2), blk, 0, stream>>>(
        nullptr, linw, linb, t1, N, 256,
        z, tag, embw, tembw,
        (const float*)nullptr, (const float*)nullptr, (const float*)nullptr,
        (const float*)nullptr,
        NULL_EPI);
    //    h = silu(t1 @ lin2w^T + b)
    gemm_fused<256, PRO_NONE, EPI_STORE><<<dim3(mbN, 2), blk, 0, stream>>>(
        t1, lin2w, lin2b, h, N, 256, NULL_PRO, NULL_EPI);

    // 3) interaction blocks
    for (int l = 0; l < 3; ++l) {
        // hd = silu(h @ down_w[l]^T + b)
        gemm_fused<256, PRO_NONE, EPI_STORE><<<dim3(mbN, 1), blk, 0, stream>>>(
            h, downw + (size_t)l * 128 * 256, downb + (size_t)l * 128, hd, N, 128,
            NULL_PRO, NULL_EPI);
        hipMemsetAsync(agg, 0, (size_t)N * 128 * sizeof(float), stream);
        hipMemsetAsync(stats, 0, 256 * sizeof(float), stream);
        // e_l = silu(e @ geom_w[l]^T + b); agg[dst] += hd[src]*e_l
        gemm_fused<128, PRO_NONE, EPI_SCATTER><<<dim3(mbE, 1), blk, 0, stream>>>(
            e, geomw + (size_t)l * 128 * 128, geomb + (size_t)l * 128,
            (float*)nullptr, E, 128,
            NULL_PRO, esrc, edst, hd, agg);
        gn_stats<<<dim3(256), blk, 0, stream>>>(agg, stats, N);
        gn_finalize<<<dim3(1), dim3(128), 0, stream>>>(
            stats, gnw + (size_t)l * 128, gnb + (size_t)l * 128,
            gnms + (size_t)l * 128, ab, 1.0f / (float)N);
        // h += silu(silu(a*agg+b) @ up_w[l]^T + up_b)
        gemm_fused<128, PRO_AFF, EPI_RESID><<<dim3(mbN, 2), blk, 0, stream>>>(
            agg, upw + (size_t)l * 256 * 128, upb + (size_t)l * 256, h, N, 256,
            (const int*)nullptr, (const int*)nullptr,
            ab, (const float*)nullptr, (const float*)nullptr, (const float*)nullptr,
            (const float*)nullptr, (const float*)nullptr,
            NULL_EPI);
    }

    // 4) readout: h1 = silu(h @ o1w^T + b); out[batch] += h1 @ o2w^T + b
    gemm_fused<256, PRO_NONE, EPI_STORE><<<dim3(mbN, 1), blk, 0, stream>>>(
        h, o1w, o1b, h1, N, 128, NULL_PRO, NULL_EPI);
    hipMemsetAsync(d_out, 0, 32 * sizeof(float), stream);
    out_reduce<<<dim3(128), blk, 0, stream>>>(h1, o2w, o2b, batch, (float*)d_out, N);
}

// Round 2
// 4517.154 us; speedup vs baseline: 1.5818x; 1.5818x over previous
//
#include <hip/hip_runtime.h>
#include <math.h>

// FAENet forward, fp32 GEMMs + dst-sorted scatter.
// Edges are counting-sorted by dst once per call; the edge-embedding GEMM
// writes e (bf16) already permuted into sorted order, so the 3 scatter-GEMMs
// read e contiguously and their epilogues combine same-dst runs in registers
// before atomically accumulating into agg (atomics ~3.4x fewer, contention
// block-local instead of global).
//
// ws layout: h[N*256] | hd[N*128] | agg[N*128] | stats | ab | cnt[N] |
//            src_s[E] | dst_s[E] | e_bf16[E*128]  (~314 MB)
// aliases: t1/h1 over hd(+agg); rank[E] over agg (dead before agg first used).

#define EPS_GN 1e-5f

__device__ __forceinline__ float silu_f(float x) {
    return x / (1.0f + __expf(-x));
}
__device__ __forceinline__ float bf2f(unsigned int u) {
    union { unsigned int i; float f; } c;
    c.i = u << 16;
    return c.f;
}
__device__ __forceinline__ unsigned int f2bf(float x) {
    union { float f; unsigned int i; } c;
    c.f = x;
    unsigned int r = c.i + 0x7fffu + ((c.i >> 16) & 1u);
    return r >> 16;
}

enum { PRO_NONE = 0, PRO_EMB = 1, PRO_EDGE = 2, PRO_AFF = 3, PRO_EBF16 = 4 };
enum { EPI_STORE = 0, EPI_SCATTER = 1, EPI_RESID = 2, EPI_PERM_BF16 = 3 };

template<int K, int PRO, int EPI>
__global__ __launch_bounds__(256)
void gemm_fused(const float* __restrict__ A, const float* __restrict__ W,
                const float* __restrict__ bias, float* __restrict__ C,
                int M, int NFTOT,
                const int* __restrict__ iz, const int* __restrict__ itag,
                const float* __restrict__ p0, const float* __restrict__ p1,
                const float* __restrict__ p2, const float* __restrict__ p3,
                const float* __restrict__ p4, const float* __restrict__ p5,
                const int* __restrict__ esrc, const int* __restrict__ edst,
                const float* __restrict__ hd, float* __restrict__ agg)
{
    __shared__ __align__(16) float As[32 * 132];
    __shared__ __align__(16) float Bs[32 * 132];

    const int tid = threadIdx.x;
    const int m0 = blockIdx.x * 128;
    const int n0 = blockIdx.y * 128;
    const int tx = tid & 15;   // feature dir
    const int ty = tid >> 4;   // row dir
    const int ar = tid >> 3;        // 0..31 (staging row / b-col)
    const int ac = (tid & 7) << 2;  // 0..28 (staging k, x4)

    float acc[8][8];
#pragma unroll
    for (int i = 0; i < 8; ++i)
#pragma unroll
        for (int j = 0; j < 8; ++j) acc[i][j] = 0.0f;

    for (int k0 = 0; k0 < K; k0 += 32) {
        // ---- stage A tile (transposed: As[k][m]) ----
#pragma unroll
        for (int i = 0; i < 4; ++i) {
            int row = m0 + ar + 32 * i;
            int rc = row < M ? row : M - 1;
            float4 v;
            if (PRO == PRO_NONE) {
                v = *(const float4*)(A + (size_t)rc * K + k0 + ac);
            } else if (PRO == PRO_EBF16) {
                const unsigned short* ep =
                    (const unsigned short*)A + (size_t)rc * K + k0 + ac;
                uint2 u = *(const uint2*)ep;
                v.x = bf2f(u.x & 0xffffu);
                v.y = bf2f(u.x >> 16);
                v.z = bf2f(u.y & 0xffffu);
                v.w = bf2f(u.y >> 16);
            } else if (PRO == PRO_AFF) {
                float4 t = *(const float4*)(A + (size_t)rc * K + k0 + ac);
                float4 a4 = *(const float4*)(p0 + k0 + ac);
                float4 b4 = *(const float4*)(p0 + 128 + k0 + ac);
                v.x = silu_f(a4.x * t.x + b4.x);
                v.y = silu_f(a4.y * t.y + b4.y);
                v.z = silu_f(a4.z * t.z + b4.z);
                v.w = silu_f(a4.w * t.w + b4.w);
            } else if (PRO == PRO_EMB) {
                int kg = k0 + ac;
                if (kg < 224) v = *(const float4*)(p0 + (size_t)iz[rc] * 224 + kg);
                else          v = *(const float4*)(p1 + (size_t)itag[rc] * 32 + (kg - 224));
            } else { // PRO_EDGE
                int kg = k0 + ac;
                if (kg < 64) {
                    float x = p0[(size_t)rc * 3 + 0];
                    float y = p0[(size_t)rc * 3 + 1];
                    float z2 = p0[(size_t)rc * 3 + 2];
#pragma unroll
                    for (int c = 0; c < 4; ++c) {
                        int kk = kg + c;
                        float s = p2[kk * 3 + 0] * x + p2[kk * 3 + 1] * y +
                                  p2[kk * 3 + 2] * z2 + p3[kk];
                        ((float*)&v)[c] = silu_f(s);
                    }
                } else {
                    int g = kg - 64;
                    float s0 = p5[g + 0], s1 = p5[g + 1], s2v = p5[g + 2], s3 = p5[g + 3];
                    const float* ea = p1 + (size_t)rc * 50;
                    const float* w0 = p4 + (size_t)g * 50;
                    for (int j = 0; j < 50; ++j) {
                        float ev = ea[j];
                        s0  = fmaf(ev, w0[j],        s0);
                        s1  = fmaf(ev, w0[50 + j],   s1);
                        s2v = fmaf(ev, w0[100 + j],  s2v);
                        s3  = fmaf(ev, w0[150 + j],  s3);
                    }
                    v = make_float4(silu_f(s0), silu_f(s1), silu_f(s2v), silu_f(s3));
                }
            }
            As[(ac + 0) * 132 + ar + 32 * i] = v.x;
            As[(ac + 1) * 132 + ar + 32 * i] = v.y;
            As[(ac + 2) * 132 + ar + 32 * i] = v.z;
            As[(ac + 3) * 132 + ar + 32 * i] = v.w;
        }
        // ---- stage B tile (W[f][k] -> Bs[k][f]) ----
#pragma unroll
        for (int i = 0; i < 4; ++i) {
            int c = ar + 32 * i;
            float4 w = *(const float4*)(W + (size_t)(n0 + c) * K + k0 + ac);
            Bs[(ac + 0) * 132 + c] = w.x;
            Bs[(ac + 1) * 132 + c] = w.y;
            Bs[(ac + 2) * 132 + c] = w.z;
            Bs[(ac + 3) * 132 + c] = w.w;
        }
        __syncthreads();
#pragma unroll
        for (int k = 0; k < 32; ++k) {
            float4 a0 = *(const float4*)(As + k * 132 + ty * 4);
            float4 a1 = *(const float4*)(As + k * 132 + 64 + ty * 4);
            float4 b0 = *(const float4*)(Bs + k * 132 + tx * 4);
            float4 b1 = *(const float4*)(Bs + k * 132 + 64 + tx * 4);
            float av[8] = {a0.x, a0.y, a0.z, a0.w, a1.x, a1.y, a1.z, a1.w};
            float bv[8] = {b0.x, b0.y, b0.z, b0.w, b1.x, b1.y, b1.z, b1.w};
#pragma unroll
            for (int i = 0; i < 8; ++i)
#pragma unroll
                for (int j = 0; j < 8; ++j)
                    acc[i][j] = fmaf(av[i], bv[j], acc[i][j]);
        }
        __syncthreads();
    }

    // ---- epilogue ----
    float4 bi0 = *(const float4*)(bias + n0 + tx * 4);
    float4 bi1 = *(const float4*)(bias + n0 + 64 + tx * 4);
    float bb[8] = {bi0.x, bi0.y, bi0.z, bi0.w, bi1.x, bi1.y, bi1.z, bi1.w};

    if (EPI == EPI_SCATTER) {
        // rows are dst-sorted: combine same-dst runs within each 4-row group
        float o[8][8];
#pragma unroll
        for (int i = 0; i < 8; ++i)
#pragma unroll
            for (int j = 0; j < 8; ++j) o[i][j] = silu_f(acc[i][j] + bb[j]);
#pragma unroll
        for (int g = 0; g < 2; ++g) {
            int rbase = m0 + g * 64 + ty * 4;
            float accf[8];
            int cur = -1;
#pragma unroll
            for (int i2 = 0; i2 < 4; ++i2) {
                int r = rbase + i2;
                if (r < M) {
                    int ii = g * 4 + i2;
                    int s = esrc[r], d = edst[r];
                    const float* hr = hd + (size_t)s * 128;
                    float4 h0 = *(const float4*)(hr + tx * 4);
                    float4 h1v = *(const float4*)(hr + 64 + tx * 4);
                    float msg[8] = {o[ii][0] * h0.x,  o[ii][1] * h0.y,
                                    o[ii][2] * h0.z,  o[ii][3] * h0.w,
                                    o[ii][4] * h1v.x, o[ii][5] * h1v.y,
                                    o[ii][6] * h1v.z, o[ii][7] * h1v.w};
                    if (d == cur) {
#pragma unroll
                        for (int j = 0; j < 8; ++j) accf[j] += msg[j];
                    } else {
                        if (cur >= 0) {
                            float* arow = agg + (size_t)cur * 128;
#pragma unroll
                            for (int j = 0; j < 4; ++j)
                                atomicAdd(arow + tx * 4 + j, accf[j]);
#pragma unroll
                            for (int j = 0; j < 4; ++j)
                                atomicAdd(arow + 64 + tx * 4 + j, accf[4 + j]);
                        }
                        cur = d;
#pragma unroll
                        for (int j = 0; j < 8; ++j) accf[j] = msg[j];
                    }
                }
            }
            if (cur >= 0) {
                float* arow = agg + (size_t)cur * 128;
#pragma unroll
                for (int j = 0; j < 4; ++j)
                    atomicAdd(arow + tx * 4 + j, accf[j]);
#pragma unroll
                for (int j = 0; j < 4; ++j)
                    atomicAdd(arow + 64 + tx * 4 + j, accf[4 + j]);
            }
        }
        return;
    }

#pragma unroll
    for (int i = 0; i < 8; ++i) {
        int rloc = (i < 4) ? (ty * 4 + i) : (64 + ty * 4 + i - 4);
        int r = m0 + rloc;
        if (r >= M) continue;
        float o[8];
#pragma unroll
        for (int j = 0; j < 8; ++j) o[j] = silu_f(acc[i][j] + bb[j]);
        if (EPI == EPI_STORE) {
            *(float4*)(C + (size_t)r * NFTOT + n0 + tx * 4) =
                make_float4(o[0], o[1], o[2], o[3]);
            *(float4*)(C + (size_t)r * NFTOT + n0 + 64 + tx * 4) =
                make_float4(o[4], o[5], o[6], o[7]);
        } else if (EPI == EPI_RESID) {
            float* c0 = C + (size_t)r * NFTOT + n0 + tx * 4;
            float* c1 = C + (size_t)r * NFTOT + n0 + 64 + tx * 4;
            float4 h0 = *(float4*)c0, h1v = *(float4*)c1;
            h0.x += o[0]; h0.y += o[1]; h0.z += o[2]; h0.w += o[3];
            h1v.x += o[4]; h1v.y += o[5]; h1v.z += o[6]; h1v.w += o[7];
            *(float4*)c0 = h0;
            *(float4*)c1 = h1v;
        } else { // EPI_PERM_BF16: write row r to bf16 C at sorted position rank[r]
            int p = esrc[r];  // rank
            unsigned short* crow = (unsigned short*)C + (size_t)p * 128;
            unsigned int w0 = f2bf(o[0]) | (f2bf(o[1]) << 16);
            unsigned int w1 = f2bf(o[2]) | (f2bf(o[3]) << 16);
            unsigned int w2v = f2bf(o[4]) | (f2bf(o[5]) << 16);
            unsigned int w3 = f2bf(o[6]) | (f2bf(o[7]) << 16);
            *(uint2*)(crow + tx * 4) = make_uint2(w0, w1);
            *(uint2*)(crow + 64 + tx * 4) = make_uint2(w2v, w3);
        }
    }
}

// ---- counting sort by dst ----
__global__ __launch_bounds__(256)
void edge_hist(const int* __restrict__ dst, int* __restrict__ cnt, int E)
{
    for (int i = blockIdx.x * 256 + threadIdx.x; i < E; i += gridDim.x * 256)
        atomicAdd(&cnt[dst[i]], 1);
}

// in-place exclusive scan of cnt[0..N-1] (single block, 1024 threads)
__global__ __launch_bounds__(1024)
void scan_excl(int* __restrict__ cnt, int N)
{
    __shared__ int sdata[1024];
    __shared__ int s_carry;
    int tid = threadIdx.x;
    if (tid == 0) s_carry = 0;
    __syncthreads();
    for (int base = 0; base < N; base += 1024) {
        int i = base + tid;
        int v = (i < N) ? cnt[i] : 0;
        sdata[tid] = v;
        __syncthreads();
        for (int off = 1; off < 1024; off <<= 1) {
            int t = (tid >= off) ? sdata[tid - off] : 0;
            __syncthreads();
            sdata[tid] += t;
            __syncthreads();
        }
        int excl = sdata[tid] - v + s_carry;
        if (i < N) cnt[i] = excl;
        int tot = sdata[1023];
        __syncthreads();
        if (tid == 0) s_carry += tot;
        __syncthreads();
    }
}

__global__ __launch_bounds__(256)
void edge_rank(const int* __restrict__ src, const int* __restrict__ dst,
               int* __restrict__ cursor, int* __restrict__ rank,
               int* __restrict__ src_s, int* __restrict__ dst_s, int E)
{
    for (int i = blockIdx.x * 256 + threadIdx.x; i < E; i += gridDim.x * 256) {
        int d = dst[i];
        int p = atomicAdd(&cursor[d], 1);
        rank[i] = p;
        src_s[p] = src[i];
        dst_s[p] = d;
    }
}

// per-feature sum and sumsq of agg[N][128] -> sums[0:128]=sum, sums[128:256]=sumsq
__global__ __launch_bounds__(256)
void gn_stats(const float* __restrict__ agg, float* __restrict__ sums, int N)
{
    __shared__ float red[512];
    int f = threadIdx.x & 127;
    int sub = threadIdx.x >> 7;
    float s = 0.f, s2 = 0.f;
    for (int r = blockIdx.x * 2 + sub; r < N; r += gridDim.x * 2) {
        float v = agg[(size_t)r * 128 + f];
        s += v;
        s2 += v * v;
    }
    red[threadIdx.x] = s;
    red[256 + threadIdx.x] = s2;
    __syncthreads();
    if (sub == 0) {
        s = red[f] + red[128 + f];
        s2 = red[256 + f] + red[384 + f];
        atomicAdd(&sums[f], s);
        atomicAdd(&sums[128 + f], s2);
    }
}

__global__ void gn_finalize(const float* __restrict__ sums,
                            const float* __restrict__ gnw, const float* __restrict__ gnb,
                            const float* __restrict__ gnms, float* __restrict__ ab,
                            float invN)
{
    int f = threadIdx.x; // 128
    float mean = sums[f] * invN;
    float ex2 = sums[128 + f] * invN;
    float m2 = mean * gnms[f];
    float var = ex2 - 2.f * m2 * mean + m2 * m2;
    float rstd = 1.0f / sqrtf(var + EPS_GN);
    float a = gnw[f] * rstd;
    ab[f] = a;
    ab[128 + f] = gnb[f] - a * m2;
}

__global__ __launch_bounds__(256)
void out_reduce(const float* __restrict__ h1, const float* __restrict__ w2,
                const float* __restrict__ b2, const int* __restrict__ batch,
                float* __restrict__ out, int N)
{
    int lane = threadIdx.x & 63;
    int wid = blockIdx.x * 4 + (threadIdx.x >> 6);
    int nw = gridDim.x * 4;
    float wa = w2[lane], wb = w2[64 + lane];
    float bb = b2[0];
    for (int r = wid; r < N; r += nw) {
        float v = h1[(size_t)r * 128 + lane] * wa + h1[(size_t)r * 128 + 64 + lane] * wb;
#pragma unroll
        for (int off = 32; off > 0; off >>= 1) v += __shfl_down(v, off);
        if (lane == 0) atomicAdd(&out[batch[r]], v + bb);
    }
}

#define NULL_PRO (const int*)nullptr, (const int*)nullptr, (const float*)nullptr, \
                 (const float*)nullptr, (const float*)nullptr, (const float*)nullptr, \
                 (const float*)nullptr, (const float*)nullptr
#define NULL_EPI (const int*)nullptr, (const int*)nullptr, (const float*)nullptr, \
                 (float*)nullptr

extern "C" void kernel_launch(void* const* d_in, const int* in_sizes, int n_in,
                              void* d_out, int out_size, void* d_ws, size_t ws_size,
                              hipStream_t stream)
{
    const int*   z         = (const int*)d_in[0];
    const int*   tag       = (const int*)d_in[1];
    const float* rel_pos   = (const float*)d_in[2];
    const float* edge_attr = (const float*)d_in[3];
    const int*   eidx      = (const int*)d_in[4];
    const int*   batch     = (const int*)d_in[5];
    const float* le1w  = (const float*)d_in[6];
    const float* le1b  = (const float*)d_in[7];
    const float* le12w = (const float*)d_in[8];
    const float* le12b = (const float*)d_in[9];
    const float* le2w  = (const float*)d_in[10];
    const float* le2b  = (const float*)d_in[11];
    const float* embw  = (const float*)d_in[12];
    const float* tembw = (const float*)d_in[13];
    const float* linw  = (const float*)d_in[14];
    const float* linb  = (const float*)d_in[15];
    const float* lin2w = (const float*)d_in[16];
    const float* lin2b = (const float*)d_in[17];
    const float* geomw = (const float*)d_in[18];
    const float* geomb = (const float*)d_in[19];
    const float* downw = (const float*)d_in[20];
    const float* downb = (const float*)d_in[21];
    const float* upw   = (const float*)d_in[22];
    const float* upb   = (const float*)d_in[23];
    const float* gnw   = (const float*)d_in[24];
    const float* gnb   = (const float*)d_in[25];
    const float* gnms  = (const float*)d_in[26];
    const float* o1w   = (const float*)d_in[27];
    const float* o1b   = (const float*)d_in[28];
    const float* o2w   = (const float*)d_in[29];
    const float* o2b   = (const float*)d_in[30];

    const int N = in_sizes[0];
    const int E = in_sizes[2] / 3;
    const int* esrc = eidx;
    const int* edst = eidx + E;

    float* ws = (float*)d_ws;
    float* h     = ws;                         // N*256
    float* hd    = h + (size_t)N * 256;        // N*128
    float* agg   = hd + (size_t)N * 128;       // N*128
    float* stats = agg + (size_t)N * 128;      // 256
    float* ab    = stats + 256;                // 256
    int*   cnt   = (int*)(ab + 256);           // N (becomes cursor after scan)
    int*   src_s = cnt + N;                    // E
    int*   dst_s = src_s + E;                  // E
    unsigned short* ebf = (unsigned short*)(dst_s + E); // E*128 bf16
    int*   rank = (int*)agg;   // alias: dead before agg first memset
    float* t1   = hd;          // alias: N*256 over hd+agg, dead before hd written
    float* h1   = hd;          // alias: written after hd's last read

    const int mbE = (E + 127) / 128;
    const int mbN = (N + 127) / 128;
    dim3 blk(256);

    // 0) counting sort of edges by dst
    hipMemsetAsync(cnt, 0, (size_t)N * sizeof(int), stream);
    edge_hist<<<dim3(3125), blk, 0, stream>>>(edst, cnt, E);
    scan_excl<<<dim3(1), dim3(1024), 0, stream>>>(cnt, N);
    edge_rank<<<dim3(3125), blk, 0, stream>>>(esrc, edst, cnt, rank, src_s, dst_s, E);

    // 1) edge embedding -> bf16, permuted into dst-sorted order
    gemm_fused<128, PRO_EDGE, EPI_PERM_BF16><<<dim3(mbE, 1), blk, 0, stream>>>(
        nullptr, le2w, le2b, (float*)ebf, E, 128,
        (const int*)nullptr, (const int*)nullptr,
        rel_pos, edge_attr, le1w, le1b, le12w, le12b,
        rank, (const int*)nullptr, (const float*)nullptr, (float*)nullptr);

    // 2) node embedding
    gemm_fused<256, PRO_EMB, EPI_STORE><<<dim3(mbN, 2), blk, 0, stream>>>(
        nullptr, linw, linb, t1, N, 256,
        z, tag, embw, tembw,
        (const float*)nullptr, (const float*)nullptr, (const float*)nullptr,
        (const float*)nullptr,
        NULL_EPI);
    gemm_fused<256, PRO_NONE, EPI_STORE><<<dim3(mbN, 2), blk, 0, stream>>>(
        t1, lin2w, lin2b, h, N, 256, NULL_PRO, NULL_EPI);

    // 3) interaction blocks
    for (int l = 0; l < 3; ++l) {
        gemm_fused<256, PRO_NONE, EPI_STORE><<<dim3(mbN, 1), blk, 0, stream>>>(
            h, downw + (size_t)l * 128 * 256, downb + (size_t)l * 128, hd, N, 128,
            NULL_PRO, NULL_EPI);
        hipMemsetAsync(agg, 0, (size_t)N * 128 * sizeof(float), stream);
        hipMemsetAsync(stats, 0, 256 * sizeof(float), stream);
        gemm_fused<128, PRO_EBF16, EPI_SCATTER><<<dim3(mbE, 1), blk, 0, stream>>>(
            (const float*)ebf, geomw + (size_t)l * 128 * 128, geomb + (size_t)l * 128,
            (float*)nullptr, E, 128,
            NULL_PRO, src_s, dst_s, hd, agg);
        gn_stats<<<dim3(256), blk, 0, stream>>>(agg, stats, N);
        gn_finalize<<<dim3(1), dim3(128), 0, stream>>>(
            stats, gnw + (size_t)l * 128, gnb + (size_t)l * 128,
            gnms + (size_t)l * 128, ab, 1.0f / (float)N);
        gemm_fused<128, PRO_AFF, EPI_RESID><<<dim3(mbN, 2), blk, 0, stream>>>(
            agg, upw + (size_t)l * 256 * 128, upb + (size_t)l * 256, h, N, 256,
            (const int*)nullptr, (const int*)nullptr,
            ab, (const float*)nullptr, (const float*)nullptr, (const float*)nullptr,
            (const float*)nullptr, (const float*)nullptr,
            NULL_EPI);
    }

    // 4) readout
    gemm_fused<256, PRO_NONE, EPI_STORE><<<dim3(mbN, 1), blk, 0, stream>>>(
        h, o1w, o1b, h1, N, 128, NULL_PRO, NULL_EPI);
    hipMemsetAsync(d_out, 0, 32 * sizeof(float), stream);
    out_reduce<<<dim3(128), blk, 0, stream>>>(h1, o2w, o2b, batch, (float*)d_out, N);
}

// Round 3
// 4201.262 us; speedup vs baseline: 1.7007x; 1.0752x over previous
//
#include <hip/hip_runtime.h>
#include <math.h>

// FAENet forward, fp32 GEMMs + dst-sorted edges + CSR segment-sum (no atomics).
// Pipeline: counting-sort edges by dst; edge-embed GEMM writes e (bf16) already
// permuted into sorted order; per layer: down-GEMM (h->hd bf16), el-GEMM
// (e->el bf16), CSR gather (one wave per node: agg[d] = sum el[p]*hd[src[p]]),
// GraphNorm stats/finalize, up-GEMM residual.
//
// ws layout (floats): h[N*256] | hdb[N*64(bf16 N*128)] | agg[N*128] | stats(256)
//   | ab(256) | cnt[N] | src_s[E] | ebf[E*64(bf16)] | el[E*64(bf16)]  ~503 MB
// aliases: rank[E](int) and t1[N*256](f32) over el region (dead before el used);
//          h1[N*128](f32) over agg (written after agg's last read).

#define EPS_GN 1e-5f

__device__ __forceinline__ float silu_f(float x) {
    return x / (1.0f + __expf(-x));
}
__device__ __forceinline__ float bf2f(unsigned int u) {
    union { unsigned int i; float f; } c;
    c.i = u << 16;
    return c.f;
}
__device__ __forceinline__ unsigned int f2bf(float x) {
    union { float f; unsigned int i; } c;
    c.f = x;
    unsigned int r = c.i + 0x7fffu + ((c.i >> 16) & 1u);
    return r >> 16;
}

enum { PRO_NONE = 0, PRO_EMB = 1, PRO_EDGE = 2, PRO_AFF = 3, PRO_EBF16 = 4 };
enum { EPI_STORE = 0, EPI_STORE_BF16 = 1, EPI_RESID = 2, EPI_PERM_BF16 = 3 };

template<int K, int PRO, int EPI>
__global__ __launch_bounds__(256)
void gemm_fused(const float* __restrict__ A, const float* __restrict__ W,
                const float* __restrict__ bias, float* __restrict__ C,
                int M, int NFTOT,
                const int* __restrict__ iz, const int* __restrict__ itag,
                const float* __restrict__ p0, const float* __restrict__ p1,
                const float* __restrict__ p2, const float* __restrict__ p3,
                const float* __restrict__ p4, const float* __restrict__ p5,
                const int* __restrict__ perm)
{
    __shared__ __align__(16) float As[32 * 132];
    __shared__ __align__(16) float Bs[32 * 132];

    const int tid = threadIdx.x;
    const int m0 = blockIdx.x * 128;
    const int n0 = blockIdx.y * 128;
    const int tx = tid & 15;   // feature dir
    const int ty = tid >> 4;   // row dir
    const int ar = tid >> 3;        // 0..31 (staging row / b-col)
    const int ac = (tid & 7) << 2;  // 0..28 (staging k, x4)

    float acc[8][8];
#pragma unroll
    for (int i = 0; i < 8; ++i)
#pragma unroll
        for (int j = 0; j < 8; ++j) acc[i][j] = 0.0f;

    for (int k0 = 0; k0 < K; k0 += 32) {
        // ---- stage A tile (transposed: As[k][m]) ----
#pragma unroll
        for (int i = 0; i < 4; ++i) {
            int row = m0 + ar + 32 * i;
            int rc = row < M ? row : M - 1;
            float4 v;
            if (PRO == PRO_NONE) {
                v = *(const float4*)(A + (size_t)rc * K + k0 + ac);
            } else if (PRO == PRO_EBF16) {
                const unsigned short* ep =
                    (const unsigned short*)A + (size_t)rc * K + k0 + ac;
                uint2 u = *(const uint2*)ep;
                v.x = bf2f(u.x & 0xffffu);
                v.y = bf2f(u.x >> 16);
                v.z = bf2f(u.y & 0xffffu);
                v.w = bf2f(u.y >> 16);
            } else if (PRO == PRO_AFF) {
                float4 t = *(const float4*)(A + (size_t)rc * K + k0 + ac);
                float4 a4 = *(const float4*)(p0 + k0 + ac);
                float4 b4 = *(const float4*)(p0 + 128 + k0 + ac);
                v.x = silu_f(a4.x * t.x + b4.x);
                v.y = silu_f(a4.y * t.y + b4.y);
                v.z = silu_f(a4.z * t.z + b4.z);
                v.w = silu_f(a4.w * t.w + b4.w);
            } else if (PRO == PRO_EMB) {
                int kg = k0 + ac;
                if (kg < 224) v = *(const float4*)(p0 + (size_t)iz[rc] * 224 + kg);
                else          v = *(const float4*)(p1 + (size_t)itag[rc] * 32 + (kg - 224));
            } else { // PRO_EDGE
                int kg = k0 + ac;
                if (kg < 64) {
                    float x = p0[(size_t)rc * 3 + 0];
                    float y = p0[(size_t)rc * 3 + 1];
                    float z2 = p0[(size_t)rc * 3 + 2];
#pragma unroll
                    for (int c = 0; c < 4; ++c) {
                        int kk = kg + c;
                        float s = p2[kk * 3 + 0] * x + p2[kk * 3 + 1] * y +
                                  p2[kk * 3 + 2] * z2 + p3[kk];
                        ((float*)&v)[c] = silu_f(s);
                    }
                } else {
                    int g = kg - 64;
                    float s0 = p5[g + 0], s1 = p5[g + 1], s2v = p5[g + 2], s3 = p5[g + 3];
                    const float* ea = p1 + (size_t)rc * 50;
                    const float* w0 = p4 + (size_t)g * 50;
                    for (int j = 0; j < 50; ++j) {
                        float ev = ea[j];
                        s0  = fmaf(ev, w0[j],        s0);
                        s1  = fmaf(ev, w0[50 + j],   s1);
                        s2v = fmaf(ev, w0[100 + j],  s2v);
                        s3  = fmaf(ev, w0[150 + j],  s3);
                    }
                    v = make_float4(silu_f(s0), silu_f(s1), silu_f(s2v), silu_f(s3));
                }
            }
            As[(ac + 0) * 132 + ar + 32 * i] = v.x;
            As[(ac + 1) * 132 + ar + 32 * i] = v.y;
            As[(ac + 2) * 132 + ar + 32 * i] = v.z;
            As[(ac + 3) * 132 + ar + 32 * i] = v.w;
        }
        // ---- stage B tile (W[f][k] -> Bs[k][f]) ----
#pragma unroll
        for (int i = 0; i < 4; ++i) {
            int c = ar + 32 * i;
            float4 w = *(const float4*)(W + (size_t)(n0 + c) * K + k0 + ac);
            Bs[(ac + 0) * 132 + c] = w.x;
            Bs[(ac + 1) * 132 + c] = w.y;
            Bs[(ac + 2) * 132 + c] = w.z;
            Bs[(ac + 3) * 132 + c] = w.w;
        }
        __syncthreads();
#pragma unroll
        for (int k = 0; k < 32; ++k) {
            float4 a0 = *(const float4*)(As + k * 132 + ty * 4);
            float4 a1 = *(const float4*)(As + k * 132 + 64 + ty * 4);
            float4 b0 = *(const float4*)(Bs + k * 132 + tx * 4);
            float4 b1 = *(const float4*)(Bs + k * 132 + 64 + tx * 4);
            float av[8] = {a0.x, a0.y, a0.z, a0.w, a1.x, a1.y, a1.z, a1.w};
            float bv[8] = {b0.x, b0.y, b0.z, b0.w, b1.x, b1.y, b1.z, b1.w};
#pragma unroll
            for (int i = 0; i < 8; ++i)
#pragma unroll
                for (int j = 0; j < 8; ++j)
                    acc[i][j] = fmaf(av[i], bv[j], acc[i][j]);
        }
        __syncthreads();
    }

    // ---- epilogue ----
    float4 bi0 = *(const float4*)(bias + n0 + tx * 4);
    float4 bi1 = *(const float4*)(bias + n0 + 64 + tx * 4);
    float bb[8] = {bi0.x, bi0.y, bi0.z, bi0.w, bi1.x, bi1.y, bi1.z, bi1.w};

#pragma unroll
    for (int i = 0; i < 8; ++i) {
        int rloc = (i < 4) ? (ty * 4 + i) : (64 + ty * 4 + i - 4);
        int r = m0 + rloc;
        if (r >= M) continue;
        float o[8];
#pragma unroll
        for (int j = 0; j < 8; ++j) o[j] = silu_f(acc[i][j] + bb[j]);
        if (EPI == EPI_STORE) {
            *(float4*)(C + (size_t)r * NFTOT + n0 + tx * 4) =
                make_float4(o[0], o[1], o[2], o[3]);
            *(float4*)(C + (size_t)r * NFTOT + n0 + 64 + tx * 4) =
                make_float4(o[4], o[5], o[6], o[7]);
        } else if (EPI == EPI_RESID) {
            float* c0 = C + (size_t)r * NFTOT + n0 + tx * 4;
            float* c1 = C + (size_t)r * NFTOT + n0 + 64 + tx * 4;
            float4 h0 = *(float4*)c0, h1v = *(float4*)c1;
            h0.x += o[0]; h0.y += o[1]; h0.z += o[2]; h0.w += o[3];
            h1v.x += o[4]; h1v.y += o[5]; h1v.z += o[6]; h1v.w += o[7];
            *(float4*)c0 = h0;
            *(float4*)c1 = h1v;
        } else { // EPI_STORE_BF16 / EPI_PERM_BF16
            int p = (EPI == EPI_PERM_BF16) ? perm[r] : r;
            unsigned short* crow = (unsigned short*)C + (size_t)p * NFTOT + n0;
            unsigned int w0 = f2bf(o[0]) | (f2bf(o[1]) << 16);
            unsigned int w1 = f2bf(o[2]) | (f2bf(o[3]) << 16);
            unsigned int w2v = f2bf(o[4]) | (f2bf(o[5]) << 16);
            unsigned int w3 = f2bf(o[6]) | (f2bf(o[7]) << 16);
            *(uint2*)(crow + tx * 4) = make_uint2(w0, w1);
            *(uint2*)(crow + 64 + tx * 4) = make_uint2(w2v, w3);
        }
    }
}

// ---- counting sort by dst ----
__global__ __launch_bounds__(256)
void edge_hist(const int* __restrict__ dst, int* __restrict__ cnt, int E)
{
    for (int i = blockIdx.x * 256 + threadIdx.x; i < E; i += gridDim.x * 256)
        atomicAdd(&cnt[dst[i]], 1);
}

// in-place exclusive scan of cnt[0..N-1] (single block, 1024 threads)
__global__ __launch_bounds__(1024)
void scan_excl(int* __restrict__ cnt, int N)
{
    __shared__ int sdata[1024];
    __shared__ int s_carry;
    int tid = threadIdx.x;
    if (tid == 0) s_carry = 0;
    __syncthreads();
    for (int base = 0; base < N; base += 1024) {
        int i = base + tid;
        int v = (i < N) ? cnt[i] : 0;
        sdata[tid] = v;
        __syncthreads();
        for (int off = 1; off < 1024; off <<= 1) {
            int t = (tid >= off) ? sdata[tid - off] : 0;
            __syncthreads();
            sdata[tid] += t;
            __syncthreads();
        }
        int excl = sdata[tid] - v + s_carry;
        if (i < N) cnt[i] = excl;
        int tot = sdata[1023];
        __syncthreads();
        if (tid == 0) s_carry += tot;
        __syncthreads();
    }
}

// scatter edges to sorted positions; afterwards cursor[d] == row-end of node d
__global__ __launch_bounds__(256)
void edge_rank(const int* __restrict__ src, const int* __restrict__ dst,
               int* __restrict__ cursor, int* __restrict__ rank,
               int* __restrict__ src_s, int E)
{
    for (int i = blockIdx.x * 256 + threadIdx.x; i < E; i += gridDim.x * 256) {
        int d = dst[i];
        int p = atomicAdd(&cursor[d], 1);
        rank[i] = p;
        src_s[p] = src[i];
    }
}

// CSR segment-sum: one wave per node d; agg[d] = sum_{p in [start,end)} el[p]*hd[src_s[p]]
// el, hd are bf16 [.,128]; each lane owns features 2*lane, 2*lane+1.
__global__ __launch_bounds__(256)
void csr_gather(const unsigned int* __restrict__ el2,   // E x 64 uints
                const unsigned int* __restrict__ hd2,   // N x 64 uints
                const int* __restrict__ src_s,
                const int* __restrict__ rowend,
                float* __restrict__ agg, int N)
{
    int lane = threadIdx.x & 63;
    int d = blockIdx.x * 4 + (threadIdx.x >> 6);
    if (d >= N) return;
    int start = (d == 0) ? 0 : rowend[d - 1];
    int end = rowend[d];
    float a0 = 0.f, a1 = 0.f;
    int p = start;
    for (; p + 1 < end; p += 2) {
        int s0 = src_s[p], s1 = src_s[p + 1];
        unsigned int e0 = el2[(size_t)p * 64 + lane];
        unsigned int h0 = hd2[(size_t)s0 * 64 + lane];
        unsigned int e1 = el2[(size_t)(p + 1) * 64 + lane];
        unsigned int h1 = hd2[(size_t)s1 * 64 + lane];
        a0 = fmaf(bf2f(e0 & 0xffffu), bf2f(h0 & 0xffffu), a0);
        a1 = fmaf(bf2f(e0 >> 16),     bf2f(h0 >> 16),     a1);
        a0 = fmaf(bf2f(e1 & 0xffffu), bf2f(h1 & 0xffffu), a0);
        a1 = fmaf(bf2f(e1 >> 16),     bf2f(h1 >> 16),     a1);
    }
    if (p < end) {
        int s0 = src_s[p];
        unsigned int e0 = el2[(size_t)p * 64 + lane];
        unsigned int h0 = hd2[(size_t)s0 * 64 + lane];
        a0 = fmaf(bf2f(e0 & 0xffffu), bf2f(h0 & 0xffffu), a0);
        a1 = fmaf(bf2f(e0 >> 16),     bf2f(h0 >> 16),     a1);
    }
    *(float2*)(agg + (size_t)d * 128 + 2 * lane) = make_float2(a0, a1);
}

// per-feature sum and sumsq of agg[N][128] -> sums[0:128]=sum, sums[128:256]=sumsq
__global__ __launch_bounds__(256)
void gn_stats(const float* __restrict__ agg, float* __restrict__ sums, int N)
{
    __shared__ float red[512];
    int f = threadIdx.x & 127;
    int sub = threadIdx.x >> 7;
    float s = 0.f, s2 = 0.f;
    for (int r = blockIdx.x * 2 + sub; r < N; r += gridDim.x * 2) {
        float v = agg[(size_t)r * 128 + f];
        s += v;
        s2 += v * v;
    }
    red[threadIdx.x] = s;
    red[256 + threadIdx.x] = s2;
    __syncthreads();
    if (sub == 0) {
        s = red[f] + red[128 + f];
        s2 = red[256 + f] + red[384 + f];
        atomicAdd(&sums[f], s);
        atomicAdd(&sums[128 + f], s2);
    }
}

__global__ void gn_finalize(const float* __restrict__ sums,
                            const float* __restrict__ gnw, const float* __restrict__ gnb,
                            const float* __restrict__ gnms, float* __restrict__ ab,
                            float invN)
{
    int f = threadIdx.x; // 128
    float mean = sums[f] * invN;
    float ex2 = sums[128 + f] * invN;
    float m2 = mean * gnms[f];
    float var = ex2 - 2.f * m2 * mean + m2 * m2;
    float rstd = 1.0f / sqrtf(var + EPS_GN);
    float a = gnw[f] * rstd;
    ab[f] = a;
    ab[128 + f] = gnb[f] - a * m2;
}

__global__ __launch_bounds__(256)
void out_reduce(const float* __restrict__ h1, const float* __restrict__ w2,
                const float* __restrict__ b2, const int* __restrict__ batch,
                float* __restrict__ out, int N)
{
    int lane = threadIdx.x & 63;
    int wid = blockIdx.x * 4 + (threadIdx.x >> 6);
    int nw = gridDim.x * 4;
    float wa = w2[lane], wb = w2[64 + lane];
    float bb = b2[0];
    for (int r = wid; r < N; r += nw) {
        float v = h1[(size_t)r * 128 + lane] * wa + h1[(size_t)r * 128 + 64 + lane] * wb;
#pragma unroll
        for (int off = 32; off > 0; off >>= 1) v += __shfl_down(v, off);
        if (lane == 0) atomicAdd(&out[batch[r]], v + bb);
    }
}

#define NULL_PRO (const int*)nullptr, (const int*)nullptr, (const float*)nullptr, \
                 (const float*)nullptr, (const float*)nullptr, (const float*)nullptr, \
                 (const float*)nullptr, (const float*)nullptr

extern "C" void kernel_launch(void* const* d_in, const int* in_sizes, int n_in,
                              void* d_out, int out_size, void* d_ws, size_t ws_size,
                              hipStream_t stream)
{
    const int*   z         = (const int*)d_in[0];
    const int*   tag       = (const int*)d_in[1];
    const float* rel_pos   = (const float*)d_in[2];
    const float* edge_attr = (const float*)d_in[3];
    const int*   eidx      = (const int*)d_in[4];
    const int*   batch     = (const int*)d_in[5];
    const float* le1w  = (const float*)d_in[6];
    const float* le1b  = (const float*)d_in[7];
    const float* le12w = (const float*)d_in[8];
    const float* le12b = (const float*)d_in[9];
    const float* le2w  = (const float*)d_in[10];
    const float* le2b  = (const float*)d_in[11];
    const float* embw  = (const float*)d_in[12];
    const float* tembw = (const float*)d_in[13];
    const float* linw  = (const float*)d_in[14];
    const float* linb  = (const float*)d_in[15];
    const float* lin2w = (const float*)d_in[16];
    const float* lin2b = (const float*)d_in[17];
    const float* geomw = (const float*)d_in[18];
    const float* geomb = (const float*)d_in[19];
    const float* downw = (const float*)d_in[20];
    const float* downb = (const float*)d_in[21];
    const float* upw   = (const float*)d_in[22];
    const float* upb   = (const float*)d_in[23];
    const float* gnw   = (const float*)d_in[24];
    const float* gnb   = (const float*)d_in[25];
    const float* gnms  = (const float*)d_in[26];
    const float* o1w   = (const float*)d_in[27];
    const float* o1b   = (const float*)d_in[28];
    const float* o2w   = (const float*)d_in[29];
    const float* o2b   = (const float*)d_in[30];

    const int N = in_sizes[0];
    const int E = in_sizes[2] / 3;
    const int* esrc = eidx;
    const int* edst = eidx + E;

    float* ws = (float*)d_ws;
    float* h     = ws;                               // N*256 f32
    unsigned short* hdb = (unsigned short*)(h + (size_t)N * 256);   // N*128 bf16
    float* agg   = (float*)(hdb + (size_t)N * 128);  // N*128 f32
    float* stats = agg + (size_t)N * 128;            // 256
    float* ab    = stats + 256;                      // 256
    int*   cnt   = (int*)(ab + 256);                 // N (row-end after edge_rank)
    int*   src_s = cnt + N;                          // E
    unsigned short* ebf = (unsigned short*)(src_s + E);       // E*128 bf16
    unsigned short* el  = ebf + (size_t)E * 128;              // E*128 bf16
    int*   rank = (int*)el;   // alias: dead before el first written
    float* t1   = (float*)el; // alias: N*256, dead before el first written
    float* h1   = agg;        // alias: written after agg's last read

    const int mbE = (E + 127) / 128;
    const int mbN = (N + 127) / 128;
    dim3 blk(256);

    // 0) counting sort of edges by dst
    hipMemsetAsync(cnt, 0, (size_t)N * sizeof(int), stream);
    edge_hist<<<dim3(3125), blk, 0, stream>>>(edst, cnt, E);
    scan_excl<<<dim3(1), dim3(1024), 0, stream>>>(cnt, N);
    edge_rank<<<dim3(3125), blk, 0, stream>>>(esrc, edst, cnt, rank, src_s, E);

    // 1) edge embedding -> bf16, permuted into dst-sorted order
    gemm_fused<128, PRO_EDGE, EPI_PERM_BF16><<<dim3(mbE, 1), blk, 0, stream>>>(
        nullptr, le2w, le2b, (float*)ebf, E, 128,
        (const int*)nullptr, (const int*)nullptr,
        rel_pos, edge_attr, le1w, le1b, le12w, le12b,
        rank);

    // 2) node embedding
    gemm_fused<256, PRO_EMB, EPI_STORE><<<dim3(mbN, 2), blk, 0, stream>>>(
        nullptr, linw, linb, t1, N, 256,
        z, tag, embw, tembw,
        (const float*)nullptr, (const float*)nullptr, (const float*)nullptr,
        (const float*)nullptr, (const int*)nullptr);
    gemm_fused<256, PRO_NONE, EPI_STORE><<<dim3(mbN, 2), blk, 0, stream>>>(
        t1, lin2w, lin2b, h, N, 256, NULL_PRO, (const int*)nullptr);

    // 3) interaction blocks
    for (int l = 0; l < 3; ++l) {
        // hd (bf16) = silu(h @ down_w^T + b)
        gemm_fused<256, PRO_NONE, EPI_STORE_BF16><<<dim3(mbN, 1), blk, 0, stream>>>(
            h, downw + (size_t)l * 128 * 256, downb + (size_t)l * 128,
            (float*)hdb, N, 128, NULL_PRO, (const int*)nullptr);
        // el (bf16) = silu(e @ geom_w^T + b)
        gemm_fused<128, PRO_EBF16, EPI_STORE_BF16><<<dim3(mbE, 1), blk, 0, stream>>>(
            (const float*)ebf, geomw + (size_t)l * 128 * 128, geomb + (size_t)l * 128,
            (float*)el, E, 128, NULL_PRO, (const int*)nullptr);
        // agg = CSR segment-sum of el * hd[src]
        csr_gather<<<dim3((N + 3) / 4), blk, 0, stream>>>(
            (const unsigned int*)el, (const unsigned int*)hdb, src_s, cnt, agg, N);
        hipMemsetAsync(stats, 0, 256 * sizeof(float), stream);
        gn_stats<<<dim3(256), blk, 0, stream>>>(agg, stats, N);
        gn_finalize<<<dim3(1), dim3(128), 0, stream>>>(
            stats, gnw + (size_t)l * 128, gnb + (size_t)l * 128,
            gnms + (size_t)l * 128, ab, 1.0f / (float)N);
        // h += silu(silu(a*agg+b) @ up_w^T + up_b)
        gemm_fused<128, PRO_AFF, EPI_RESID><<<dim3(mbN, 2), blk, 0, stream>>>(
            agg, upw + (size_t)l * 256 * 128, upb + (size_t)l * 256, h, N, 256,
            (const int*)nullptr, (const int*)nullptr,
            ab, (const float*)nullptr, (const float*)nullptr, (const float*)nullptr,
            (const float*)nullptr, (const float*)nullptr,
            (const int*)nullptr);
    }

    // 4) readout
    gemm_fused<256, PRO_NONE, EPI_STORE><<<dim3(mbN, 1), blk, 0, stream>>>(
        h, o1w, o1b, h1, N, 128, NULL_PRO, (const int*)nullptr);
    hipMemsetAsync(d_out, 0, 32 * sizeof(float), stream);
    out_reduce<<<dim3(128), blk, 0, stream>>>(h1, o2w, o2b, batch, (float*)d_out, N);
}

// Round 4
// 3165.643 us; speedup vs baseline: 2.2571x; 1.3271x over previous
//
#include <hip/hip_runtime.h>
#include <math.h>

// FAENet forward. All GEMMs via bf16 MFMA (16x16x32), fp32 accumulate.
// Per-wave 64x64 output (16 mfma tiles), 4 waves -> 128x128 block, no LDS,
// A/B frags loaded direct from global in MFMA operand layout
// [row=lane&15][k=(lane>>4)*8+j]. W preloaded to registers when K==128.
//
// ws layout (bytes):
//   T   204.8MB : t_e bf16[E*128] -> (hb0 f32[N*256] | t1 f32[N*256]) -> el bf16[E*128]
//   ebf 204.8MB : e bf16[E*128], dst-sorted
//   h    51.2MB : f32[N*256] residual stream
//   agg  25.6MB : f32[N*128]  (aliases: rank[E] early, h1[N*128] late)
//   hdb  12.8MB : bf16[N*128] hd  (alias: ga bf16[N*128] after csr_gather)
//   cnt/src_s/wbuf/stats/ab : ~4.3MB       total ~503.5MB

#define EPS_GN 1e-5f

typedef __attribute__((ext_vector_type(8))) short bf16x8;
typedef __attribute__((ext_vector_type(4))) float f32x4;

__device__ __forceinline__ float silu_f(float x) {
    return x / (1.0f + __expf(-x));
}
__device__ __forceinline__ float bf2f(unsigned int u) {
    union { unsigned int i; float f; } c;
    c.i = u << 16;
    return c.f;
}
__device__ __forceinline__ unsigned int f2bf(float x) {
    union { float f; unsigned int i; } c;
    c.f = x;
    unsigned int r = c.i + 0x7fffu + ((c.i >> 16) & 1u);
    return r >> 16;
}

enum { A_BF16 = 0, A_F32 = 1 };
enum { ME_STORE_F32 = 0, ME_STORE_BF16 = 1, ME_PERM_BF16 = 2, ME_RESID = 3 };

// C[M x NFTOT] = epi(A[M x K] @ W[NFTOT x K]^T + bias), MFMA bf16.
template<int K, int AMODE, int EPI, bool PRELW>
__global__ __launch_bounds__(256)
void mgemm(const void* __restrict__ Ap, const unsigned short* __restrict__ Wp,
           const float* __restrict__ bias, float* __restrict__ Cf,
           unsigned short* __restrict__ Cb, int M, int NFTOT,
           const int* __restrict__ perm)
{
    constexpr int KS = K / 32;
    const int tid = threadIdx.x;
    const int lane = tid & 63;
    const int wv = tid >> 6;                    // 0..3
    const int l16 = lane & 15;
    const int quad = lane >> 4;                 // 0..3
    const int m0 = blockIdx.x * 128 + (wv >> 1) * 64;
    const int n0 = blockIdx.y * 128 + (wv & 1) * 64;

    // preload W fragments (K=128: 16 frags = 64 VGPRs)
    bf16x8 wpre[PRELW ? (KS * 4) : 1];
    if (PRELW) {
#pragma unroll
        for (int t = 0; t < 4; ++t)
#pragma unroll
            for (int s = 0; s < KS; ++s)
                wpre[t * KS + s] = *(const bf16x8*)(Wp +
                    (size_t)(n0 + 16 * t + l16) * K + s * 32 + quad * 8);
    }

    f32x4 acc[4][4];
#pragma unroll
    for (int i = 0; i < 4; ++i)
#pragma unroll
        for (int j = 0; j < 4; ++j) acc[i][j] = (f32x4){0.f, 0.f, 0.f, 0.f};

    for (int s = 0; s < KS; ++s) {
        bf16x8 af[4];
#pragma unroll
        for (int t = 0; t < 4; ++t) {
            int r = m0 + 16 * t + l16;
            if (r >= M) r = M - 1;
            if (AMODE == A_BF16) {
                af[t] = *(const bf16x8*)((const unsigned short*)Ap +
                                         (size_t)r * K + s * 32 + quad * 8);
            } else {
                const float* ap = (const float*)Ap + (size_t)r * K + s * 32 + quad * 8;
                float4 x0 = *(const float4*)ap;
                float4 x1 = *(const float4*)(ap + 4);
                bf16x8 v;
                v[0] = (short)f2bf(x0.x); v[1] = (short)f2bf(x0.y);
                v[2] = (short)f2bf(x0.z); v[3] = (short)f2bf(x0.w);
                v[4] = (short)f2bf(x1.x); v[5] = (short)f2bf(x1.y);
                v[6] = (short)f2bf(x1.z); v[7] = (short)f2bf(x1.w);
                af[t] = v;
            }
        }
        bf16x8 wf[4];
#pragma unroll
        for (int t = 0; t < 4; ++t) {
            if (PRELW) wf[t] = wpre[t * KS + s];
            else       wf[t] = *(const bf16x8*)(Wp +
                           (size_t)(n0 + 16 * t + l16) * K + s * 32 + quad * 8);
        }
#pragma unroll
        for (int tm = 0; tm < 4; ++tm)
#pragma unroll
            for (int tn = 0; tn < 4; ++tn)
                acc[tm][tn] = __builtin_amdgcn_mfma_f32_16x16x32_bf16(
                    af[tm], wf[tn], acc[tm][tn], 0, 0, 0);
    }

    // epilogue: D[row=quad*4+reg][col=l16] per 16x16 tile
#pragma unroll
    for (int tn = 0; tn < 4; ++tn) {
        int c = n0 + 16 * tn + l16;
        float bv = bias[c];
#pragma unroll
        for (int tm = 0; tm < 4; ++tm) {
            int rb = m0 + 16 * tm + quad * 4;
#pragma unroll
            for (int rg = 0; rg < 4; ++rg) {
                int r = rb + rg;
                if (r >= M) continue;
                float v = silu_f(acc[tm][tn][rg] + bv);
                if (EPI == ME_STORE_F32) {
                    Cf[(size_t)r * NFTOT + c] = v;
                } else if (EPI == ME_STORE_BF16) {
                    Cb[(size_t)r * NFTOT + c] = (unsigned short)f2bf(v);
                } else if (EPI == ME_PERM_BF16) {
                    Cb[(size_t)perm[r] * NFTOT + c] = (unsigned short)f2bf(v);
                } else { // ME_RESID
                    Cf[(size_t)r * NFTOT + c] += v;
                }
            }
        }
    }
}

// t_e[e][0:64]  = silu(rel_pos[e] @ le1w^T + b1)
// t_e[e][64:128]= silu(edge_attr[e] @ le12w^T + b12)   (bf16 out)
__global__ __launch_bounds__(256)
void edge_feat(const float* __restrict__ rp, const float* __restrict__ ea,
               const float* __restrict__ w1, const float* __restrict__ b1,
               const float* __restrict__ w12, const float* __restrict__ b12,
               unsigned short* __restrict__ te, int E)
{
    __shared__ float sw[64 * 51];
    for (int i = threadIdx.x; i < 3200; i += 256) {
        int rr = i / 50, cc = i - rr * 50;
        sw[rr * 51 + cc] = w12[i];
    }
    __syncthreads();
    int lane = threadIdx.x & 63;
    int wv = threadIdx.x >> 6;
    const float w1x = w1[lane * 3], w1y = w1[lane * 3 + 1], w1z = w1[lane * 3 + 2];
    const float bb1 = b1[lane], bb2 = b12[lane];
    const float* swr = sw + lane * 51;
    int step = gridDim.x * 16;
    for (int e0 = (blockIdx.x * 4 + wv) * 4; e0 < E; e0 += step) {
        if (e0 + 3 < E) {
            const float* a0 = ea + (size_t)e0 * 50;
            float s0 = bb2, s1 = bb2, s2 = bb2, s3 = bb2;
            for (int j = 0; j < 50; ++j) {
                float w = swr[j];
                s0 = fmaf(a0[j],       w, s0);
                s1 = fmaf(a0[50 + j],  w, s1);
                s2 = fmaf(a0[100 + j], w, s2);
                s3 = fmaf(a0[150 + j], w, s3);
            }
            float sv[4] = {s0, s1, s2, s3};
#pragma unroll
            for (int u = 0; u < 4; ++u) {
                int e = e0 + u;
                float t1v = w1x * rp[3 * e] + w1y * rp[3 * e + 1] +
                            w1z * rp[3 * e + 2] + bb1;
                te[(size_t)e * 128 + lane] = (unsigned short)f2bf(silu_f(t1v));
                te[(size_t)e * 128 + 64 + lane] = (unsigned short)f2bf(silu_f(sv[u]));
            }
        } else {
            for (int e = e0; e < E; ++e) {
                float s2 = bb2;
                const float* ar = ea + (size_t)e * 50;
                for (int j = 0; j < 50; ++j) s2 = fmaf(ar[j], swr[j], s2);
                float t1v = w1x * rp[3 * e] + w1y * rp[3 * e + 1] +
                            w1z * rp[3 * e + 2] + bb1;
                te[(size_t)e * 128 + lane] = (unsigned short)f2bf(silu_f(t1v));
                te[(size_t)e * 128 + 64 + lane] = (unsigned short)f2bf(silu_f(s2));
            }
        }
    }
}

// hb0[n][0:224]=emb_w[z[n]], [224:256]=tag_emb_w[tag[n]]  (f32)
__global__ __launch_bounds__(256)
void node_gather(const int* __restrict__ z, const int* __restrict__ tag,
                 const float* __restrict__ embw, const float* __restrict__ tembw,
                 float* __restrict__ hb0, int N)
{
    int lane = threadIdx.x & 63;
    int n = blockIdx.x * 4 + (threadIdx.x >> 6);
    if (n >= N) return;
    int f = lane * 4;
    float4 v;
    if (f < 224) v = *(const float4*)(embw + (size_t)z[n] * 224 + f);
    else         v = *(const float4*)(tembw + (size_t)tag[n] * 32 + (f - 224));
    *(float4*)(hb0 + (size_t)n * 256 + f) = v;
}

__global__ __launch_bounds__(256)
void cvt_bf16(const float* __restrict__ src, unsigned short* __restrict__ dst, int n)
{
    int i = blockIdx.x * 256 + threadIdx.x;
    if (i < n) dst[i] = (unsigned short)f2bf(src[i]);
}

// ---- counting sort by dst ----
__global__ __launch_bounds__(256)
void edge_hist(const int* __restrict__ dst, int* __restrict__ cnt, int E)
{
    for (int i = blockIdx.x * 256 + threadIdx.x; i < E; i += gridDim.x * 256)
        atomicAdd(&cnt[dst[i]], 1);
}

__global__ __launch_bounds__(1024)
void scan_excl(int* __restrict__ cnt, int N)
{
    __shared__ int sdata[1024];
    __shared__ int s_carry;
    int tid = threadIdx.x;
    if (tid == 0) s_carry = 0;
    __syncthreads();
    for (int base = 0; base < N; base += 1024) {
        int i = base + tid;
        int v = (i < N) ? cnt[i] : 0;
        sdata[tid] = v;
        __syncthreads();
        for (int off = 1; off < 1024; off <<= 1) {
            int t = (tid >= off) ? sdata[tid - off] : 0;
            __syncthreads();
            sdata[tid] += t;
            __syncthreads();
        }
        int excl = sdata[tid] - v + s_carry;
        if (i < N) cnt[i] = excl;
        int tot = sdata[1023];
        __syncthreads();
        if (tid == 0) s_carry += tot;
        __syncthreads();
    }
}

__global__ __launch_bounds__(256)
void edge_rank(const int* __restrict__ src, const int* __restrict__ dst,
               int* __restrict__ cursor, int* __restrict__ rank,
               int* __restrict__ src_s, int E)
{
    for (int i = blockIdx.x * 256 + threadIdx.x; i < E; i += gridDim.x * 256) {
        int d = dst[i];
        int p = atomicAdd(&cursor[d], 1);
        rank[i] = p;
        src_s[p] = src[i];
    }
}

// CSR segment-sum: one wave per node d; agg[d] = sum el[p]*hd[src_s[p]]
__global__ __launch_bounds__(256)
void csr_gather(const unsigned int* __restrict__ el2,   // E x 64 uints (bf16x2)
                const unsigned int* __restrict__ hd2,   // N x 64 uints
                const int* __restrict__ src_s,
                const int* __restrict__ rowend,
                float* __restrict__ agg, int N)
{
    int lane = threadIdx.x & 63;
    int d = blockIdx.x * 4 + (threadIdx.x >> 6);
    if (d >= N) return;
    int start = (d == 0) ? 0 : rowend[d - 1];
    int end = rowend[d];
    float a0 = 0.f, a1 = 0.f;
    int p = start;
    for (; p + 1 < end; p += 2) {
        int s0 = src_s[p], s1 = src_s[p + 1];
        unsigned int e0 = el2[(size_t)p * 64 + lane];
        unsigned int h0 = hd2[(size_t)s0 * 64 + lane];
        unsigned int e1 = el2[(size_t)(p + 1) * 64 + lane];
        unsigned int h1 = hd2[(size_t)s1 * 64 + lane];
        a0 = fmaf(bf2f(e0 & 0xffffu), bf2f(h0 & 0xffffu), a0);
        a1 = fmaf(bf2f(e0 >> 16),     bf2f(h0 >> 16),     a1);
        a0 = fmaf(bf2f(e1 & 0xffffu), bf2f(h1 & 0xffffu), a0);
        a1 = fmaf(bf2f(e1 >> 16),     bf2f(h1 >> 16),     a1);
    }
    if (p < end) {
        int s0 = src_s[p];
        unsigned int e0 = el2[(size_t)p * 64 + lane];
        unsigned int h0 = hd2[(size_t)s0 * 64 + lane];
        a0 = fmaf(bf2f(e0 & 0xffffu), bf2f(h0 & 0xffffu), a0);
        a1 = fmaf(bf2f(e0 >> 16),     bf2f(h0 >> 16),     a1);
    }
    *(float2*)(agg + (size_t)d * 128 + 2 * lane) = make_float2(a0, a1);
}

__global__ __launch_bounds__(256)
void gn_stats(const float* __restrict__ agg, float* __restrict__ sums, int N)
{
    __shared__ float red[512];
    int f = threadIdx.x & 127;
    int sub = threadIdx.x >> 7;
    float s = 0.f, s2 = 0.f;
    for (int r = blockIdx.x * 2 + sub; r < N; r += gridDim.x * 2) {
        float v = agg[(size_t)r * 128 + f];
        s += v;
        s2 += v * v;
    }
    red[threadIdx.x] = s;
    red[256 + threadIdx.x] = s2;
    __syncthreads();
    if (sub == 0) {
        s = red[f] + red[128 + f];
        s2 = red[256 + f] + red[384 + f];
        atomicAdd(&sums[f], s);
        atomicAdd(&sums[128 + f], s2);
    }
}

__global__ void gn_finalize(const float* __restrict__ sums,
                            const float* __restrict__ gnw, const float* __restrict__ gnb,
                            const float* __restrict__ gnms, float* __restrict__ ab,
                            float invN)
{
    int f = threadIdx.x; // 128
    float mean = sums[f] * invN;
    float ex2 = sums[128 + f] * invN;
    float m2 = mean * gnms[f];
    float var = ex2 - 2.f * m2 * mean + m2 * m2;
    float rstd = 1.0f / sqrtf(var + EPS_GN);
    float a = gnw[f] * rstd;
    ab[f] = a;
    ab[128 + f] = gnb[f] - a * m2;
}

// ga = bf16(silu(a*agg+b)) elementwise
__global__ __launch_bounds__(256)
void gn_apply(const float* __restrict__ agg, const float* __restrict__ ab,
              unsigned int* __restrict__ ga, int n2 /* N*64 */)
{
    for (int i = blockIdx.x * 256 + threadIdx.x; i < n2; i += gridDim.x * 256) {
        int f = (i & 63) * 2;
        float2 v = *(const float2*)(agg + (size_t)i * 2);
        float r0 = silu_f(ab[f] * v.x + ab[128 + f]);
        float r1 = silu_f(ab[f + 1] * v.y + ab[129 + f]);
        ga[i] = f2bf(r0) | (f2bf(r1) << 16);
    }
}

__global__ __launch_bounds__(256)
void out_reduce(const float* __restrict__ h1, const float* __restrict__ w2,
                const float* __restrict__ b2, const int* __restrict__ batch,
                float* __restrict__ out, int N)
{
    int lane = threadIdx.x & 63;
    int wid = blockIdx.x * 4 + (threadIdx.x >> 6);
    int nw = gridDim.x * 4;
    float wa = w2[lane], wb = w2[64 + lane];
    float bb = b2[0];
    for (int r = wid; r < N; r += nw) {
        float v = h1[(size_t)r * 128 + lane] * wa + h1[(size_t)r * 128 + 64 + lane] * wb;
#pragma unroll
        for (int off = 32; off > 0; off >>= 1) v += __shfl_down(v, off);
        if (lane == 0) atomicAdd(&out[batch[r]], v + bb);
    }
}

extern "C" void kernel_launch(void* const* d_in, const int* in_sizes, int n_in,
                              void* d_out, int out_size, void* d_ws, size_t ws_size,
                              hipStream_t stream)
{
    const int*   z         = (const int*)d_in[0];
    const int*   tag       = (const int*)d_in[1];
    const float* rel_pos   = (const float*)d_in[2];
    const float* edge_attr = (const float*)d_in[3];
    const int*   eidx      = (const int*)d_in[4];
    const int*   batch     = (const int*)d_in[5];
    const float* le1w  = (const float*)d_in[6];
    const float* le1b  = (const float*)d_in[7];
    const float* le12w = (const float*)d_in[8];
    const float* le12b = (const float*)d_in[9];
    const float* le2w  = (const float*)d_in[10];
    const float* le2b  = (const float*)d_in[11];
    const float* embw  = (const float*)d_in[12];
    const float* tembw = (const float*)d_in[13];
    const float* linw  = (const float*)d_in[14];
    const float* linb  = (const float*)d_in[15];
    const float* lin2w = (const float*)d_in[16];
    const float* lin2b = (const float*)d_in[17];
    const float* geomw = (const float*)d_in[18];
    const float* geomb = (const float*)d_in[19];
    const float* downw = (const float*)d_in[20];
    const float* downb = (const float*)d_in[21];
    const float* upw   = (const float*)d_in[22];
    const float* upb   = (const float*)d_in[23];
    const float* gnw   = (const float*)d_in[24];
    const float* gnb   = (const float*)d_in[25];
    const float* gnms  = (const float*)d_in[26];
    const float* o1w   = (const float*)d_in[27];
    const float* o1b   = (const float*)d_in[28];
    const float* o2w   = (const float*)d_in[29];
    const float* o2b   = (const float*)d_in[30];

    const int N = in_sizes[0];
    const int E = in_sizes[2] / 3;
    const int* esrc = eidx;
    const int* edst = eidx + E;

    char* ws = (char*)d_ws;
    size_t off = 0;
    unsigned short* T = (unsigned short*)(ws + off); off += (size_t)E * 128 * 2;   // t_e / hb0+t1 / el
    unsigned short* ebf = (unsigned short*)(ws + off); off += (size_t)E * 128 * 2;
    float* h   = (float*)(ws + off); off += (size_t)N * 256 * 4;
    float* agg = (float*)(ws + off); off += (size_t)N * 128 * 4;
    unsigned short* hdb = (unsigned short*)(ws + off); off += (size_t)N * 128 * 2;
    int*   cnt   = (int*)(ws + off); off += (size_t)N * 4;
    int*   src_s = (int*)(ws + off); off += (size_t)E * 4;
    unsigned short* wbuf = (unsigned short*)(ws + off); off += 425984ull * 2;
    float* stats = (float*)(ws + off); off += 256 * 4;
    float* ab    = (float*)(ws + off); off += 256 * 4;

    // aliases
    unsigned short* te  = T;                        // E*128 bf16, dead after e-embed GEMM
    float* hb0 = (float*)T;                         // N*256 f32
    float* t1  = (float*)T + (size_t)N * 256;       // N*256 f32 (both dead before layers)
    unsigned short* el = T;                         // E*128 bf16 (layers)
    int*   rank = (int*)agg;                        // E ints, dead before agg first write
    unsigned short* ga = hdb;                       // bf16 N*128, written after csr_gather
    float* h1 = agg;                                // N*128 f32, written after agg last read

    // bf16 weight buffer offsets
    unsigned short* wb_le2  = wbuf;                 // 16384
    unsigned short* wb_geom = wbuf + 16384;         // 3*16384
    unsigned short* wb_down = wbuf + 65536;         // 3*32768
    unsigned short* wb_up   = wbuf + 163840;        // 3*32768
    unsigned short* wb_lin  = wbuf + 262144;        // 65536
    unsigned short* wb_lin2 = wbuf + 327680;        // 65536
    unsigned short* wb_o1   = wbuf + 393216;        // 32768

    const int mbE = (E + 127) / 128;
    const int mbN = (N + 127) / 128;
    dim3 blk(256);

    // weight conversions
    cvt_bf16<<<dim3(64), blk, 0, stream>>>(le2w, wb_le2, 16384);
    cvt_bf16<<<dim3(192), blk, 0, stream>>>(geomw, wb_geom, 49152);
    cvt_bf16<<<dim3(384), blk, 0, stream>>>(downw, wb_down, 98304);
    cvt_bf16<<<dim3(384), blk, 0, stream>>>(upw, wb_up, 98304);
    cvt_bf16<<<dim3(256), blk, 0, stream>>>(linw, wb_lin, 65536);
    cvt_bf16<<<dim3(256), blk, 0, stream>>>(lin2w, wb_lin2, 65536);
    cvt_bf16<<<dim3(128), blk, 0, stream>>>(o1w, wb_o1, 32768);

    // counting sort by dst
    hipMemsetAsync(cnt, 0, (size_t)N * sizeof(int), stream);
    edge_hist<<<dim3(3125), blk, 0, stream>>>(edst, cnt, E);
    scan_excl<<<dim3(1), dim3(1024), 0, stream>>>(cnt, N);
    edge_rank<<<dim3(3125), blk, 0, stream>>>(esrc, edst, cnt, rank, src_s, E);

    // edge features + edge embedding (permuted into dst-sorted order)
    edge_feat<<<dim3(1024), blk, 0, stream>>>(rel_pos, edge_attr, le1w, le1b,
                                              le12w, le12b, te, E);
    mgemm<128, A_BF16, ME_PERM_BF16, true><<<dim3(mbE, 1), blk, 0, stream>>>(
        te, wb_le2, le2b, nullptr, ebf, E, 128, rank);

    // node embedding: hb0 -> t1 -> h
    node_gather<<<dim3((N + 3) / 4), blk, 0, stream>>>(z, tag, embw, tembw, hb0, N);
    mgemm<256, A_F32, ME_STORE_F32, false><<<dim3(mbN, 2), blk, 0, stream>>>(
        hb0, wb_lin, linb, t1, nullptr, N, 256, nullptr);
    mgemm<256, A_F32, ME_STORE_F32, false><<<dim3(mbN, 2), blk, 0, stream>>>(
        t1, wb_lin2, lin2b, h, nullptr, N, 256, nullptr);

    // interaction blocks
    for (int l = 0; l < 3; ++l) {
        mgemm<256, A_F32, ME_STORE_BF16, false><<<dim3(mbN, 1), blk, 0, stream>>>(
            h, wb_down + (size_t)l * 32768, downb + (size_t)l * 128,
            nullptr, hdb, N, 128, nullptr);
        mgemm<128, A_BF16, ME_STORE_BF16, true><<<dim3(mbE, 1), blk, 0, stream>>>(
            ebf, wb_geom + (size_t)l * 16384, geomb + (size_t)l * 128,
            nullptr, el, E, 128, nullptr);
        csr_gather<<<dim3((N + 3) / 4), blk, 0, stream>>>(
            (const unsigned int*)el, (const unsigned int*)hdb, src_s, cnt, agg, N);
        hipMemsetAsync(stats, 0, 256 * sizeof(float), stream);
        gn_stats<<<dim3(256), blk, 0, stream>>>(agg, stats, N);
        gn_finalize<<<dim3(1), dim3(128), 0, stream>>>(
            stats, gnw + (size_t)l * 128, gnb + (size_t)l * 128,
            gnms + (size_t)l * 128, ab, 1.0f / (float)N);
        gn_apply<<<dim3(512), blk, 0, stream>>>(agg, ab, (unsigned int*)ga, N * 64);
        mgemm<128, A_BF16, ME_RESID, true><<<dim3(mbN, 2), blk, 0, stream>>>(
            ga, wb_up + (size_t)l * 32768, upb + (size_t)l * 256,
            h, nullptr, N, 256, nullptr);
    }

    // readout
    mgemm<256, A_F32, ME_STORE_F32, false><<<dim3(mbN, 1), blk, 0, stream>>>(
        h, wb_o1, o1b, h1, nullptr, N, 128, nullptr);
    hipMemsetAsync(d_out, 0, 32 * sizeof(float), stream);
    out_reduce<<<dim3(128), blk, 0, stream>>>(h1, o2w, o2b, batch, (float*)d_out, N);
}

// Round 5
// 2670.857 us; speedup vs baseline: 2.6753x; 1.1853x over previous
//
#include <hip/hip_runtime.h>
#include <math.h>

// FAENet forward. All GEMMs via bf16 MFMA (16x16x32), fp32 accumulate.
// Per-wave 64x64 output (16 mfma tiles), 4 waves -> 128x128 block, no LDS,
// A/B frags loaded direct from global in MFMA operand layout
// [row=lane&15][k=(lane>>4)*8+j]. W preloaded to registers when K==128.
// out_reduce: contiguous per-wave chunks + run-accumulate over sorted batch
// (atomics ~2K instead of 50K onto 2 cache lines).

#define EPS_GN 1e-5f

typedef __attribute__((ext_vector_type(8))) short bf16x8;
typedef __attribute__((ext_vector_type(4))) float f32x4;

__device__ __forceinline__ float silu_f(float x) {
    return x / (1.0f + __expf(-x));
}
__device__ __forceinline__ float bf2f(unsigned int u) {
    union { unsigned int i; float f; } c;
    c.i = u << 16;
    return c.f;
}
__device__ __forceinline__ unsigned int f2bf(float x) {
    union { float f; unsigned int i; } c;
    c.f = x;
    unsigned int r = c.i + 0x7fffu + ((c.i >> 16) & 1u);
    return r >> 16;
}

enum { A_BF16 = 0, A_F32 = 1 };
enum { ME_STORE_F32 = 0, ME_STORE_BF16 = 1, ME_PERM_BF16 = 2, ME_RESID = 3 };

// C[M x NFTOT] = epi(A[M x K] @ W[NFTOT x K]^T + bias), MFMA bf16.
template<int K, int AMODE, int EPI, bool PRELW>
__global__ __launch_bounds__(256)
void mgemm(const void* __restrict__ Ap, const unsigned short* __restrict__ Wp,
           const float* __restrict__ bias, float* __restrict__ Cf,
           unsigned short* __restrict__ Cb, int M, int NFTOT,
           const int* __restrict__ perm)
{
    constexpr int KS = K / 32;
    const int tid = threadIdx.x;
    const int lane = tid & 63;
    const int wv = tid >> 6;                    // 0..3
    const int l16 = lane & 15;
    const int quad = lane >> 4;                 // 0..3
    const int m0 = blockIdx.x * 128 + (wv >> 1) * 64;
    const int n0 = blockIdx.y * 128 + (wv & 1) * 64;

    // preload W fragments (K=128: 16 frags = 64 VGPRs)
    bf16x8 wpre[PRELW ? (KS * 4) : 1];
    if (PRELW) {
#pragma unroll
        for (int t = 0; t < 4; ++t)
#pragma unroll
            for (int s = 0; s < KS; ++s)
                wpre[t * KS + s] = *(const bf16x8*)(Wp +
                    (size_t)(n0 + 16 * t + l16) * K + s * 32 + quad * 8);
    }

    f32x4 acc[4][4];
#pragma unroll
    for (int i = 0; i < 4; ++i)
#pragma unroll
        for (int j = 0; j < 4; ++j) acc[i][j] = (f32x4){0.f, 0.f, 0.f, 0.f};

    for (int s = 0; s < KS; ++s) {
        bf16x8 af[4];
#pragma unroll
        for (int t = 0; t < 4; ++t) {
            int r = m0 + 16 * t + l16;
            if (r >= M) r = M - 1;
            if (AMODE == A_BF16) {
                af[t] = *(const bf16x8*)((const unsigned short*)Ap +
                                         (size_t)r * K + s * 32 + quad * 8);
            } else {
                const float* ap = (const float*)Ap + (size_t)r * K + s * 32 + quad * 8;
                float4 x0 = *(const float4*)ap;
                float4 x1 = *(const float4*)(ap + 4);
                bf16x8 v;
                v[0] = (short)f2bf(x0.x); v[1] = (short)f2bf(x0.y);
                v[2] = (short)f2bf(x0.z); v[3] = (short)f2bf(x0.w);
                v[4] = (short)f2bf(x1.x); v[5] = (short)f2bf(x1.y);
                v[6] = (short)f2bf(x1.z); v[7] = (short)f2bf(x1.w);
                af[t] = v;
            }
        }
        bf16x8 wf[4];
#pragma unroll
        for (int t = 0; t < 4; ++t) {
            if (PRELW) wf[t] = wpre[t * KS + s];
            else       wf[t] = *(const bf16x8*)(Wp +
                           (size_t)(n0 + 16 * t + l16) * K + s * 32 + quad * 8);
        }
#pragma unroll
        for (int tm = 0; tm < 4; ++tm)
#pragma unroll
            for (int tn = 0; tn < 4; ++tn)
                acc[tm][tn] = __builtin_amdgcn_mfma_f32_16x16x32_bf16(
                    af[tm], wf[tn], acc[tm][tn], 0, 0, 0);
    }

    // epilogue: D[row=quad*4+reg][col=l16] per 16x16 tile
#pragma unroll
    for (int tn = 0; tn < 4; ++tn) {
        int c = n0 + 16 * tn + l16;
        float bv = bias[c];
#pragma unroll
        for (int tm = 0; tm < 4; ++tm) {
            int rb = m0 + 16 * tm + quad * 4;
#pragma unroll
            for (int rg = 0; rg < 4; ++rg) {
                int r = rb + rg;
                if (r >= M) continue;
                float v = silu_f(acc[tm][tn][rg] + bv);
                if (EPI == ME_STORE_F32) {
                    Cf[(size_t)r * NFTOT + c] = v;
                } else if (EPI == ME_STORE_BF16) {
                    Cb[(size_t)r * NFTOT + c] = (unsigned short)f2bf(v);
                } else if (EPI == ME_PERM_BF16) {
                    Cb[(size_t)perm[r] * NFTOT + c] = (unsigned short)f2bf(v);
                } else { // ME_RESID
                    Cf[(size_t)r * NFTOT + c] += v;
                }
            }
        }
    }
}

// t_e[e][0:64]  = silu(rel_pos[e] @ le1w^T + b1)
// t_e[e][64:128]= silu(edge_attr[e] @ le12w^T + b12)   (bf16 out)
__global__ __launch_bounds__(256)
void edge_feat(const float* __restrict__ rp, const float* __restrict__ ea,
               const float* __restrict__ w1, const float* __restrict__ b1,
               const float* __restrict__ w12, const float* __restrict__ b12,
               unsigned short* __restrict__ te, int E)
{
    __shared__ float sw[64 * 51];
    for (int i = threadIdx.x; i < 3200; i += 256) {
        int rr = i / 50, cc = i - rr * 50;
        sw[rr * 51 + cc] = w12[i];
    }
    __syncthreads();
    int lane = threadIdx.x & 63;
    int wv = threadIdx.x >> 6;
    const float w1x = w1[lane * 3], w1y = w1[lane * 3 + 1], w1z = w1[lane * 3 + 2];
    const float bb1 = b1[lane], bb2 = b12[lane];
    const float* swr = sw + lane * 51;
    int step = gridDim.x * 16;
    for (int e0 = (blockIdx.x * 4 + wv) * 4; e0 < E; e0 += step) {
        if (e0 + 3 < E) {
            const float* a0 = ea + (size_t)e0 * 50;
            float s0 = bb2, s1 = bb2, s2 = bb2, s3 = bb2;
            for (int j = 0; j < 50; ++j) {
                float w = swr[j];
                s0 = fmaf(a0[j],       w, s0);
                s1 = fmaf(a0[50 + j],  w, s1);
                s2 = fmaf(a0[100 + j], w, s2);
                s3 = fmaf(a0[150 + j], w, s3);
            }
            float sv[4] = {s0, s1, s2, s3};
#pragma unroll
            for (int u = 0; u < 4; ++u) {
                int e = e0 + u;
                float t1v = w1x * rp[3 * e] + w1y * rp[3 * e + 1] +
                            w1z * rp[3 * e + 2] + bb1;
                te[(size_t)e * 128 + lane] = (unsigned short)f2bf(silu_f(t1v));
                te[(size_t)e * 128 + 64 + lane] = (unsigned short)f2bf(silu_f(sv[u]));
            }
        } else {
            for (int e = e0; e < E; ++e) {
                float s2 = bb2;
                const float* ar = ea + (size_t)e * 50;
                for (int j = 0; j < 50; ++j) s2 = fmaf(ar[j], swr[j], s2);
                float t1v = w1x * rp[3 * e] + w1y * rp[3 * e + 1] +
                            w1z * rp[3 * e + 2] + bb1;
                te[(size_t)e * 128 + lane] = (unsigned short)f2bf(silu_f(t1v));
                te[(size_t)e * 128 + 64 + lane] = (unsigned short)f2bf(silu_f(s2));
            }
        }
    }
}

// hb0[n][0:224]=emb_w[z[n]], [224:256]=tag_emb_w[tag[n]]  (f32)
__global__ __launch_bounds__(256)
void node_gather(const int* __restrict__ z, const int* __restrict__ tag,
                 const float* __restrict__ embw, const float* __restrict__ tembw,
                 float* __restrict__ hb0, int N)
{
    int lane = threadIdx.x & 63;
    int n = blockIdx.x * 4 + (threadIdx.x >> 6);
    if (n >= N) return;
    int f = lane * 4;
    float4 v;
    if (f < 224) v = *(const float4*)(embw + (size_t)z[n] * 224 + f);
    else         v = *(const float4*)(tembw + (size_t)tag[n] * 32 + (f - 224));
    *(float4*)(hb0 + (size_t)n * 256 + f) = v;
}

__global__ __launch_bounds__(256)
void cvt_bf16(const float* __restrict__ src, unsigned short* __restrict__ dst, int n)
{
    int i = blockIdx.x * 256 + threadIdx.x;
    if (i < n) dst[i] = (unsigned short)f2bf(src[i]);
}

// ---- counting sort by dst ----
__global__ __launch_bounds__(256)
void edge_hist(const int* __restrict__ dst, int* __restrict__ cnt, int E)
{
    for (int i = blockIdx.x * 256 + threadIdx.x; i < E; i += gridDim.x * 256)
        atomicAdd(&cnt[dst[i]], 1);
}

__global__ __launch_bounds__(1024)
void scan_excl(int* __restrict__ cnt, int N)
{
    __shared__ int sdata[1024];
    __shared__ int s_carry;
    int tid = threadIdx.x;
    if (tid == 0) s_carry = 0;
    __syncthreads();
    for (int base = 0; base < N; base += 1024) {
        int i = base + tid;
        int v = (i < N) ? cnt[i] : 0;
        sdata[tid] = v;
        __syncthreads();
        for (int off = 1; off < 1024; off <<= 1) {
            int t = (tid >= off) ? sdata[tid - off] : 0;
            __syncthreads();
            sdata[tid] += t;
            __syncthreads();
        }
        int excl = sdata[tid] - v + s_carry;
        if (i < N) cnt[i] = excl;
        int tot = sdata[1023];
        __syncthreads();
        if (tid == 0) s_carry += tot;
        __syncthreads();
    }
}

__global__ __launch_bounds__(256)
void edge_rank(const int* __restrict__ src, const int* __restrict__ dst,
               int* __restrict__ cursor, int* __restrict__ rank,
               int* __restrict__ src_s, int E)
{
    for (int i = blockIdx.x * 256 + threadIdx.x; i < E; i += gridDim.x * 256) {
        int d = dst[i];
        int p = atomicAdd(&cursor[d], 1);
        rank[i] = p;
        src_s[p] = src[i];
    }
}

// CSR segment-sum: one wave per node d; agg[d] = sum el[p]*hd[src_s[p]]
__global__ __launch_bounds__(256)
void csr_gather(const unsigned int* __restrict__ el2,   // E x 64 uints (bf16x2)
                const unsigned int* __restrict__ hd2,   // N x 64 uints
                const int* __restrict__ src_s,
                const int* __restrict__ rowend,
                float* __restrict__ agg, int N)
{
    int lane = threadIdx.x & 63;
    int d = blockIdx.x * 4 + (threadIdx.x >> 6);
    if (d >= N) return;
    int start = (d == 0) ? 0 : rowend[d - 1];
    int end = rowend[d];
    float a0 = 0.f, a1 = 0.f;
    int p = start;
    for (; p + 1 < end; p += 2) {
        int s0 = src_s[p], s1 = src_s[p + 1];
        unsigned int e0 = el2[(size_t)p * 64 + lane];
        unsigned int h0 = hd2[(size_t)s0 * 64 + lane];
        unsigned int e1 = el2[(size_t)(p + 1) * 64 + lane];
        unsigned int h1 = hd2[(size_t)s1 * 64 + lane];
        a0 = fmaf(bf2f(e0 & 0xffffu), bf2f(h0 & 0xffffu), a0);
        a1 = fmaf(bf2f(e0 >> 16),     bf2f(h0 >> 16),     a1);
        a0 = fmaf(bf2f(e1 & 0xffffu), bf2f(h1 & 0xffffu), a0);
        a1 = fmaf(bf2f(e1 >> 16),     bf2f(h1 >> 16),     a1);
    }
    if (p < end) {
        int s0 = src_s[p];
        unsigned int e0 = el2[(size_t)p * 64 + lane];
        unsigned int h0 = hd2[(size_t)s0 * 64 + lane];
        a0 = fmaf(bf2f(e0 & 0xffffu), bf2f(h0 & 0xffffu), a0);
        a1 = fmaf(bf2f(e0 >> 16),     bf2f(h0 >> 16),     a1);
    }
    *(float2*)(agg + (size_t)d * 128 + 2 * lane) = make_float2(a0, a1);
}

__global__ __launch_bounds__(256)
void gn_stats(const float* __restrict__ agg, float* __restrict__ sums, int N)
{
    __shared__ float red[512];
    int f = threadIdx.x & 127;
    int sub = threadIdx.x >> 7;
    float s = 0.f, s2 = 0.f;
    for (int r = blockIdx.x * 2 + sub; r < N; r += gridDim.x * 2) {
        float v = agg[(size_t)r * 128 + f];
        s += v;
        s2 += v * v;
    }
    red[threadIdx.x] = s;
    red[256 + threadIdx.x] = s2;
    __syncthreads();
    if (sub == 0) {
        s = red[f] + red[128 + f];
        s2 = red[256 + f] + red[384 + f];
        atomicAdd(&sums[f], s);
        atomicAdd(&sums[128 + f], s2);
    }
}

__global__ void gn_finalize(const float* __restrict__ sums,
                            const float* __restrict__ gnw, const float* __restrict__ gnb,
                            const float* __restrict__ gnms, float* __restrict__ ab,
                            float invN)
{
    int f = threadIdx.x; // 128
    float mean = sums[f] * invN;
    float ex2 = sums[128 + f] * invN;
    float m2 = mean * gnms[f];
    float var = ex2 - 2.f * m2 * mean + m2 * m2;
    float rstd = 1.0f / sqrtf(var + EPS_GN);
    float a = gnw[f] * rstd;
    ab[f] = a;
    ab[128 + f] = gnb[f] - a * m2;
}

// ga = bf16(silu(a*agg+b)) elementwise
__global__ __launch_bounds__(256)
void gn_apply(const float* __restrict__ agg, const float* __restrict__ ab,
              unsigned int* __restrict__ ga, int n2 /* N*64 */)
{
    for (int i = blockIdx.x * 256 + threadIdx.x; i < n2; i += gridDim.x * 256) {
        int f = (i & 63) * 2;
        float2 v = *(const float2*)(agg + (size_t)i * 2);
        float r0 = silu_f(ab[f] * v.x + ab[128 + f]);
        float r1 = silu_f(ab[f + 1] * v.y + ab[129 + f]);
        ga[i] = f2bf(r0) | (f2bf(r1) << 16);
    }
}

// out[g] += sum over nodes of graph g of (h1[r] . w2) + b2.
// batch is sorted: each wave takes a contiguous chunk, accumulates per-lane
// partials per graph-run, reduces+atomics only at run boundaries.
__global__ __launch_bounds__(256)
void out_reduce(const float* __restrict__ h1, const float* __restrict__ w2,
                const float* __restrict__ b2, const int* __restrict__ batch,
                float* __restrict__ out, int N)
{
    int lane = threadIdx.x & 63;
    int wid = blockIdx.x * 4 + (threadIdx.x >> 6);
    int nwaves = gridDim.x * 4;
    int chunk = (N + nwaves - 1) / nwaves;
    int r0 = wid * chunk;
    int r1 = r0 + chunk; if (r1 > N) r1 = N;
    if (r0 >= r1) return;
    float wa = w2[lane], wb = w2[64 + lane];
    float bb = b2[0];
    int cur = batch[r0];
    float acc = 0.f;
    int cnt = 0;
    for (int r = r0; r < r1; ++r) {
        int g = batch[r];
        if (g != cur) {
            float v = acc;
#pragma unroll
            for (int o = 32; o > 0; o >>= 1) v += __shfl_down(v, o);
            if (lane == 0) atomicAdd(&out[cur], v + (float)cnt * bb);
            cur = g; acc = 0.f; cnt = 0;
        }
        acc = fmaf(h1[(size_t)r * 128 + lane], wa, acc);
        acc = fmaf(h1[(size_t)r * 128 + 64 + lane], wb, acc);
        ++cnt;
    }
    float v = acc;
#pragma unroll
    for (int o = 32; o > 0; o >>= 1) v += __shfl_down(v, o);
    if (lane == 0) atomicAdd(&out[cur], v + (float)cnt * bb);
}

extern "C" void kernel_launch(void* const* d_in, const int* in_sizes, int n_in,
                              void* d_out, int out_size, void* d_ws, size_t ws_size,
                              hipStream_t stream)
{
    const int*   z         = (const int*)d_in[0];
    const int*   tag       = (const int*)d_in[1];
    const float* rel_pos   = (const float*)d_in[2];
    const float* edge_attr = (const float*)d_in[3];
    const int*   eidx      = (const int*)d_in[4];
    const int*   batch     = (const int*)d_in[5];
    const float* le1w  = (const float*)d_in[6];
    const float* le1b  = (const float*)d_in[7];
    const float* le12w = (const float*)d_in[8];
    const float* le12b = (const float*)d_in[9];
    const float* le2w  = (const float*)d_in[10];
    const float* le2b  = (const float*)d_in[11];
    const float* embw  = (const float*)d_in[12];
    const float* tembw = (const float*)d_in[13];
    const float* linw  = (const float*)d_in[14];
    const float* linb  = (const float*)d_in[15];
    const float* lin2w = (const float*)d_in[16];
    const float* lin2b = (const float*)d_in[17];
    const float* geomw = (const float*)d_in[18];
    const float* geomb = (const float*)d_in[19];
    const float* downw = (const float*)d_in[20];
    const float* downb = (const float*)d_in[21];
    const float* upw   = (const float*)d_in[22];
    const float* upb   = (const float*)d_in[23];
    const float* gnw   = (const float*)d_in[24];
    const float* gnb   = (const float*)d_in[25];
    const float* gnms  = (const float*)d_in[26];
    const float* o1w   = (const float*)d_in[27];
    const float* o1b   = (const float*)d_in[28];
    const float* o2w   = (const float*)d_in[29];
    const float* o2b   = (const float*)d_in[30];

    const int N = in_sizes[0];
    const int E = in_sizes[2] / 3;
    const int* esrc = eidx;
    const int* edst = eidx + E;

    char* ws = (char*)d_ws;
    size_t off = 0;
    unsigned short* T = (unsigned short*)(ws + off); off += (size_t)E * 128 * 2;   // t_e / hb0+t1 / el
    unsigned short* ebf = (unsigned short*)(ws + off); off += (size_t)E * 128 * 2;
    float* h   = (float*)(ws + off); off += (size_t)N * 256 * 4;
    float* agg = (float*)(ws + off); off += (size_t)N * 128 * 4;
    unsigned short* hdb = (unsigned short*)(ws + off); off += (size_t)N * 128 * 2;
    int*   cnt   = (int*)(ws + off); off += (size_t)N * 4;
    int*   src_s = (int*)(ws + off); off += (size_t)E * 4;
    unsigned short* wbuf = (unsigned short*)(ws + off); off += 425984ull * 2;
    float* stats = (float*)(ws + off); off += 256 * 4;
    float* ab    = (float*)(ws + off); off += 256 * 4;

    // aliases
    unsigned short* te  = T;                        // E*128 bf16, dead after e-embed GEMM
    float* hb0 = (float*)T;                         // N*256 f32
    float* t1  = (float*)T + (size_t)N * 256;       // N*256 f32 (both dead before layers)
    unsigned short* el = T;                         // E*128 bf16 (layers)
    int*   rank = (int*)agg;                        // E ints, dead before agg first write
    unsigned short* ga = hdb;                       // bf16 N*128, written after csr_gather
    float* h1 = agg;                                // N*128 f32, written after agg last read

    // bf16 weight buffer offsets
    unsigned short* wb_le2  = wbuf;                 // 16384
    unsigned short* wb_geom = wbuf + 16384;         // 3*16384
    unsigned short* wb_down = wbuf + 65536;         // 3*32768
    unsigned short* wb_up   = wbuf + 163840;        // 3*32768
    unsigned short* wb_lin  = wbuf + 262144;        // 65536
    unsigned short* wb_lin2 = wbuf + 327680;        // 65536
    unsigned short* wb_o1   = wbuf + 393216;        // 32768

    const int mbE = (E + 127) / 128;
    const int mbN = (N + 127) / 128;
    dim3 blk(256);

    // weight conversions
    cvt_bf16<<<dim3(64), blk, 0, stream>>>(le2w, wb_le2, 16384);
    cvt_bf16<<<dim3(192), blk, 0, stream>>>(geomw, wb_geom, 49152);
    cvt_bf16<<<dim3(384), blk, 0, stream>>>(downw, wb_down, 98304);
    cvt_bf16<<<dim3(384), blk, 0, stream>>>(upw, wb_up, 98304);
    cvt_bf16<<<dim3(256), blk, 0, stream>>>(linw, wb_lin, 65536);
    cvt_bf16<<<dim3(256), blk, 0, stream>>>(lin2w, wb_lin2, 65536);
    cvt_bf16<<<dim3(128), blk, 0, stream>>>(o1w, wb_o1, 32768);

    // counting sort by dst
    hipMemsetAsync(cnt, 0, (size_t)N * sizeof(int), stream);
    edge_hist<<<dim3(3125), blk, 0, stream>>>(edst, cnt, E);
    scan_excl<<<dim3(1), dim3(1024), 0, stream>>>(cnt, N);
    edge_rank<<<dim3(3125), blk, 0, stream>>>(esrc, edst, cnt, rank, src_s, E);

    // edge features + edge embedding (permuted into dst-sorted order)
    edge_feat<<<dim3(1024), blk, 0, stream>>>(rel_pos, edge_attr, le1w, le1b,
                                              le12w, le12b, te, E);
    mgemm<128, A_BF16, ME_PERM_BF16, true><<<dim3(mbE, 1), blk, 0, stream>>>(
        te, wb_le2, le2b, nullptr, ebf, E, 128, rank);

    // node embedding: hb0 -> t1 -> h
    node_gather<<<dim3((N + 3) / 4), blk, 0, stream>>>(z, tag, embw, tembw, hb0, N);
    mgemm<256, A_F32, ME_STORE_F32, false><<<dim3(mbN, 2), blk, 0, stream>>>(
        hb0, wb_lin, linb, t1, nullptr, N, 256, nullptr);
    mgemm<256, A_F32, ME_STORE_F32, false><<<dim3(mbN, 2), blk, 0, stream>>>(
        t1, wb_lin2, lin2b, h, nullptr, N, 256, nullptr);

    // interaction blocks
    for (int l = 0; l < 3; ++l) {
        mgemm<256, A_F32, ME_STORE_BF16, false><<<dim3(mbN, 1), blk, 0, stream>>>(
            h, wb_down + (size_t)l * 32768, downb + (size_t)l * 128,
            nullptr, hdb, N, 128, nullptr);
        mgemm<128, A_BF16, ME_STORE_BF16, true><<<dim3(mbE, 1), blk, 0, stream>>>(
            ebf, wb_geom + (size_t)l * 16384, geomb + (size_t)l * 128,
            nullptr, el, E, 128, nullptr);
        csr_gather<<<dim3((N + 3) / 4), blk, 0, stream>>>(
            (const unsigned int*)el, (const unsigned int*)hdb, src_s, cnt, agg, N);
        hipMemsetAsync(stats, 0, 256 * sizeof(float), stream);
        gn_stats<<<dim3(256), blk, 0, stream>>>(agg, stats, N);
        gn_finalize<<<dim3(1), dim3(128), 0, stream>>>(
            stats, gnw + (size_t)l * 128, gnb + (size_t)l * 128,
            gnms + (size_t)l * 128, ab, 1.0f / (float)N);
        gn_apply<<<dim3(512), blk, 0, stream>>>(agg, ab, (unsigned int*)ga, N * 64);
        mgemm<128, A_BF16, ME_RESID, true><<<dim3(mbN, 2), blk, 0, stream>>>(
            ga, wb_up + (size_t)l * 32768, upb + (size_t)l * 256,
            h, nullptr, N, 256, nullptr);
    }

    // readout
    mgemm<256, A_F32, ME_STORE_F32, false><<<dim3(mbN, 1), blk, 0, stream>>>(
        h, wb_o1, o1b, h1, nullptr, N, 128, nullptr);
    hipMemsetAsync(d_out, 0, 32 * sizeof(float), stream);
    out_reduce<<<dim3(512), blk, 0, stream>>>(h1, o2w, o2b, batch, (float*)d_out, N);
}

// Round 7
// 2381.599 us; speedup vs baseline: 3.0002x; 1.1215x over previous
//
#include <hip/hip_runtime.h>
#include <math.h>

// FAENet forward. All GEMMs via bf16 MFMA (16x16x32), fp32 accumulate.
// Edge embedding fully fused: [rp|ea] -> LDS -> MFMA(K=64, Wcat) -> silu ->
// LDS (rot-swizzled) -> MFMA(K=128, le2w) -> silu -> permuted bf16 store.
// Wcat column layout MUST match sA staging: rp at k=0..2, ea at k=3..52 (r6 bug).
// out_reduce: contiguous per-wave chunks over sorted batch (~2K atomics).

#define EPS_GN 1e-5f

typedef __attribute__((ext_vector_type(8))) short bf16x8;
typedef __attribute__((ext_vector_type(4))) float f32x4;

__device__ __forceinline__ float silu_f(float x) {
    return x / (1.0f + __expf(-x));
}
__device__ __forceinline__ float bf2f(unsigned int u) {
    union { unsigned int i; float f; } c;
    c.i = u << 16;
    return c.f;
}
__device__ __forceinline__ unsigned int f2bf(float x) {
    union { float f; unsigned int i; } c;
    c.f = x;
    unsigned int r = c.i + 0x7fffu + ((c.i >> 16) & 1u);
    return r >> 16;
}

enum { A_BF16 = 0, A_F32 = 1 };
enum { ME_STORE_F32 = 0, ME_STORE_BF16 = 1, ME_PERM_BF16 = 2, ME_RESID = 3 };

// C[M x NFTOT] = epi(A[M x K] @ W[NFTOT x K]^T + bias), MFMA bf16.
template<int K, int AMODE, int EPI, bool PRELW>
__global__ __launch_bounds__(256)
void mgemm(const void* __restrict__ Ap, const unsigned short* __restrict__ Wp,
           const float* __restrict__ bias, float* __restrict__ Cf,
           unsigned short* __restrict__ Cb, int M, int NFTOT,
           const int* __restrict__ perm)
{
    constexpr int KS = K / 32;
    const int tid = threadIdx.x;
    const int lane = tid & 63;
    const int wv = tid >> 6;                    // 0..3
    const int l16 = lane & 15;
    const int quad = lane >> 4;                 // 0..3
    const int m0 = blockIdx.x * 128 + (wv >> 1) * 64;
    const int n0 = blockIdx.y * 128 + (wv & 1) * 64;

    bf16x8 wpre[PRELW ? (KS * 4) : 1];
    if (PRELW) {
#pragma unroll
        for (int t = 0; t < 4; ++t)
#pragma unroll
            for (int s = 0; s < KS; ++s)
                wpre[t * KS + s] = *(const bf16x8*)(Wp +
                    (size_t)(n0 + 16 * t + l16) * K + s * 32 + quad * 8);
    }

    f32x4 acc[4][4];
#pragma unroll
    for (int i = 0; i < 4; ++i)
#pragma unroll
        for (int j = 0; j < 4; ++j) acc[i][j] = (f32x4){0.f, 0.f, 0.f, 0.f};

    for (int s = 0; s < KS; ++s) {
        bf16x8 af[4];
#pragma unroll
        for (int t = 0; t < 4; ++t) {
            int r = m0 + 16 * t + l16;
            if (r >= M) r = M - 1;
            if (AMODE == A_BF16) {
                af[t] = *(const bf16x8*)((const unsigned short*)Ap +
                                         (size_t)r * K + s * 32 + quad * 8);
            } else {
                const float* ap = (const float*)Ap + (size_t)r * K + s * 32 + quad * 8;
                float4 x0 = *(const float4*)ap;
                float4 x1 = *(const float4*)(ap + 4);
                bf16x8 v;
                v[0] = (short)f2bf(x0.x); v[1] = (short)f2bf(x0.y);
                v[2] = (short)f2bf(x0.z); v[3] = (short)f2bf(x0.w);
                v[4] = (short)f2bf(x1.x); v[5] = (short)f2bf(x1.y);
                v[6] = (short)f2bf(x1.z); v[7] = (short)f2bf(x1.w);
                af[t] = v;
            }
        }
        bf16x8 wf[4];
#pragma unroll
        for (int t = 0; t < 4; ++t) {
            if (PRELW) wf[t] = wpre[t * KS + s];
            else       wf[t] = *(const bf16x8*)(Wp +
                           (size_t)(n0 + 16 * t + l16) * K + s * 32 + quad * 8);
        }
#pragma unroll
        for (int tm = 0; tm < 4; ++tm)
#pragma unroll
            for (int tn = 0; tn < 4; ++tn)
                acc[tm][tn] = __builtin_amdgcn_mfma_f32_16x16x32_bf16(
                    af[tm], wf[tn], acc[tm][tn], 0, 0, 0);
    }

#pragma unroll
    for (int tn = 0; tn < 4; ++tn) {
        int c = n0 + 16 * tn + l16;
        float bv = bias[c];
#pragma unroll
        for (int tm = 0; tm < 4; ++tm) {
            int rb = m0 + 16 * tm + quad * 4;
#pragma unroll
            for (int rg = 0; rg < 4; ++rg) {
                int r = rb + rg;
                if (r >= M) continue;
                float v = silu_f(acc[tm][tn][rg] + bv);
                if (EPI == ME_STORE_F32) {
                    Cf[(size_t)r * NFTOT + c] = v;
                } else if (EPI == ME_STORE_BF16) {
                    Cb[(size_t)r * NFTOT + c] = (unsigned short)f2bf(v);
                } else if (EPI == ME_PERM_BF16) {
                    Cb[(size_t)perm[r] * NFTOT + c] = (unsigned short)f2bf(v);
                } else { // ME_RESID
                    Cf[(size_t)r * NFTOT + c] += v;
                }
            }
        }
    }
}

// Wcat[128 x 64] bf16 matching sA layout [rp k=0..2 | ea k=3..52 | pad]:
// rows 0..63: le1w at cols 0..2; rows 64..127: le12w at cols 3..52; rest 0.
// bcat[128] = [le1b | le12b].
__global__ __launch_bounds__(256)
void build_wcat(const float* __restrict__ w1, const float* __restrict__ w12,
                const float* __restrict__ b1, const float* __restrict__ b12,
                unsigned short* __restrict__ wcat, float* __restrict__ bcat)
{
    int i = blockIdx.x * 256 + threadIdx.x;
    if (i < 8192) {
        int r = i >> 6, c = i & 63;
        float v = 0.f;
        if (r < 64) { if (c < 3) v = w1[r * 3 + c]; }
        else        { if (c >= 3 && c < 53) v = w12[(r - 64) * 50 + (c - 3)]; }
        wcat[i] = (unsigned short)f2bf(v);
    }
    if (i < 128) bcat[i] = (i < 64) ? b1[i] : b12[i - 64];
}

// Fused edge embedding: e[perm[r]] = silu(silu([rp|ea] @ Wcat^T + bcat) @ W2^T + b2)
__global__ __launch_bounds__(256)
void edge_embed_fused(const float* __restrict__ rp, const float* __restrict__ ea,
                      const unsigned short* __restrict__ wcat,
                      const float* __restrict__ bcat,
                      const unsigned short* __restrict__ w2,
                      const float* __restrict__ b2,
                      const int* __restrict__ perm,
                      unsigned short* __restrict__ ebf, int E)
{
    __shared__ unsigned short sA[128 * 72];   // [row][k0..63], stride 72
    __shared__ unsigned short sT[128 * 128];  // t-tile, rot-swizzled k-groups
    const int tid = threadIdx.x;
    const int m0 = blockIdx.x * 128;

    // stage [rp|ea] -> sA (bf16): rp at k=0..2, ea at k=3..52, zero-pad 53..63
    for (int i = tid; i < 128 * 11; i += 256) {
        int r = i / 11, c = i - r * 11;
        sA[r * 72 + 53 + c] = 0;
    }
    for (int i = tid; i < 384; i += 256) {
        int r = i / 3, c = i - r * 3;
        sA[r * 72 + c] = (unsigned short)f2bf(rp[(size_t)m0 * 3 + i]);
    }
    for (int i = tid; i < 6400; i += 256) {
        int r = i / 50, c = i - r * 50;
        sA[r * 72 + 3 + c] = (unsigned short)f2bf(ea[(size_t)m0 * 50 + i]);
    }
    __syncthreads();

    const int lane = tid & 63;
    const int wv = tid >> 6;
    const int l16 = lane & 15, quad = lane >> 4;
    const int mw = (wv >> 1) * 64;
    const int nw = (wv & 1) * 64;

    // stage 1: t = silu(A @ Wcat^T + bcat), K=64
    f32x4 acc[4][4];
#pragma unroll
    for (int i = 0; i < 4; ++i)
#pragma unroll
        for (int j = 0; j < 4; ++j) acc[i][j] = (f32x4){0.f, 0.f, 0.f, 0.f};
#pragma unroll
    for (int s = 0; s < 2; ++s) {
        bf16x8 af[4], wf[4];
#pragma unroll
        for (int t = 0; t < 4; ++t)
            af[t] = *(const bf16x8*)(sA + (mw + 16 * t + l16) * 72 + s * 32 + quad * 8);
#pragma unroll
        for (int t = 0; t < 4; ++t)
            wf[t] = *(const bf16x8*)(wcat +
                (size_t)(nw + 16 * t + l16) * 64 + s * 32 + quad * 8);
#pragma unroll
        for (int tm = 0; tm < 4; ++tm)
#pragma unroll
            for (int tn = 0; tn < 4; ++tn)
                acc[tm][tn] = __builtin_amdgcn_mfma_f32_16x16x32_bf16(
                    af[tm], wf[tn], acc[tm][tn], 0, 0, 0);
    }
    // silu+bias -> sT with k-group rotation swizzle: group g stored at (g+r)&15
#pragma unroll
    for (int tn = 0; tn < 4; ++tn) {
        int c = nw + 16 * tn + l16;
        float bv = bcat[c];
#pragma unroll
        for (int tm = 0; tm < 4; ++tm) {
            int rb = mw + 16 * tm + quad * 4;
#pragma unroll
            for (int rg = 0; rg < 4; ++rg) {
                int r = rb + rg;
                int g = ((c >> 3) + r) & 15;
                sT[r * 128 + g * 8 + (c & 7)] =
                    (unsigned short)f2bf(silu_f(acc[tm][tn][rg] + bv));
            }
        }
    }
    __syncthreads();

    // stage 2: e = silu(t @ W2^T + b2), K=128
    f32x4 acc2[4][4];
#pragma unroll
    for (int i = 0; i < 4; ++i)
#pragma unroll
        for (int j = 0; j < 4; ++j) acc2[i][j] = (f32x4){0.f, 0.f, 0.f, 0.f};
#pragma unroll
    for (int s = 0; s < 4; ++s) {
        bf16x8 af[4], wf[4];
#pragma unroll
        for (int t = 0; t < 4; ++t) {
            int r = mw + 16 * t + l16;
            int g = (s * 4 + quad + r) & 15;
            af[t] = *(const bf16x8*)(sT + r * 128 + g * 8);
        }
#pragma unroll
        for (int t = 0; t < 4; ++t)
            wf[t] = *(const bf16x8*)(w2 +
                (size_t)(nw + 16 * t + l16) * 128 + s * 32 + quad * 8);
#pragma unroll
        for (int tm = 0; tm < 4; ++tm)
#pragma unroll
            for (int tn = 0; tn < 4; ++tn)
                acc2[tm][tn] = __builtin_amdgcn_mfma_f32_16x16x32_bf16(
                    af[tm], wf[tn], acc2[tm][tn], 0, 0, 0);
    }
#pragma unroll
    for (int tn = 0; tn < 4; ++tn) {
        int c = nw + 16 * tn + l16;
        float bv = b2[c];
#pragma unroll
        for (int tm = 0; tm < 4; ++tm) {
            int rb = m0 + mw + 16 * tm + quad * 4;
#pragma unroll
            for (int rg = 0; rg < 4; ++rg) {
                int r = rb + rg;
                if (r >= E) continue;
                ebf[(size_t)perm[r] * 128 + c] =
                    (unsigned short)f2bf(silu_f(acc2[tm][tn][rg] + bv));
            }
        }
    }
}

// hb0[n][0:224]=emb_w[z[n]], [224:256]=tag_emb_w[tag[n]]  (f32)
__global__ __launch_bounds__(256)
void node_gather(const int* __restrict__ z, const int* __restrict__ tag,
                 const float* __restrict__ embw, const float* __restrict__ tembw,
                 float* __restrict__ hb0, int N)
{
    int lane = threadIdx.x & 63;
    int n = blockIdx.x * 4 + (threadIdx.x >> 6);
    if (n >= N) return;
    int f = lane * 4;
    float4 v;
    if (f < 224) v = *(const float4*)(embw + (size_t)z[n] * 224 + f);
    else         v = *(const float4*)(tembw + (size_t)tag[n] * 32 + (f - 224));
    *(float4*)(hb0 + (size_t)n * 256 + f) = v;
}

__global__ __launch_bounds__(256)
void cvt_bf16(const float* __restrict__ src, unsigned short* __restrict__ dst, int n)
{
    int i = blockIdx.x * 256 + threadIdx.x;
    if (i < n) dst[i] = (unsigned short)f2bf(src[i]);
}

// ---- counting sort by dst ----
__global__ __launch_bounds__(256)
void edge_hist(const int* __restrict__ dst, int* __restrict__ cnt, int E)
{
    for (int i = blockIdx.x * 256 + threadIdx.x; i < E; i += gridDim.x * 256)
        atomicAdd(&cnt[dst[i]], 1);
}

__global__ __launch_bounds__(1024)
void scan_excl(int* __restrict__ cnt, int N)
{
    __shared__ int sdata[1024];
    __shared__ int s_carry;
    int tid = threadIdx.x;
    if (tid == 0) s_carry = 0;
    __syncthreads();
    for (int base = 0; base < N; base += 1024) {
        int i = base + tid;
        int v = (i < N) ? cnt[i] : 0;
        sdata[tid] = v;
        __syncthreads();
        for (int off = 1; off < 1024; off <<= 1) {
            int t = (tid >= off) ? sdata[tid - off] : 0;
            __syncthreads();
            sdata[tid] += t;
            __syncthreads();
        }
        int excl = sdata[tid] - v + s_carry;
        if (i < N) cnt[i] = excl;
        int tot = sdata[1023];
        __syncthreads();
        if (tid == 0) s_carry += tot;
        __syncthreads();
    }
}

__global__ __launch_bounds__(256)
void edge_rank(const int* __restrict__ src, const int* __restrict__ dst,
               int* __restrict__ cursor, int* __restrict__ rank,
               int* __restrict__ src_s, int E)
{
    for (int i = blockIdx.x * 256 + threadIdx.x; i < E; i += gridDim.x * 256) {
        int d = dst[i];
        int p = atomicAdd(&cursor[d], 1);
        rank[i] = p;
        src_s[p] = src[i];
    }
}

// CSR segment-sum: one wave per node d; agg[d] = sum el[p]*hd[src_s[p]]
__global__ __launch_bounds__(256)
void csr_gather(const unsigned int* __restrict__ el2,
                const unsigned int* __restrict__ hd2,
                const int* __restrict__ src_s,
                const int* __restrict__ rowend,
                float* __restrict__ agg, int N)
{
    int lane = threadIdx.x & 63;
    int d = blockIdx.x * 4 + (threadIdx.x >> 6);
    if (d >= N) return;
    int start = (d == 0) ? 0 : rowend[d - 1];
    int end = rowend[d];
    float a0 = 0.f, a1 = 0.f;
    int p = start;
    for (; p + 1 < end; p += 2) {
        int s0 = src_s[p], s1 = src_s[p + 1];
        unsigned int e0 = el2[(size_t)p * 64 + lane];
        unsigned int h0 = hd2[(size_t)s0 * 64 + lane];
        unsigned int e1 = el2[(size_t)(p + 1) * 64 + lane];
        unsigned int h1 = hd2[(size_t)s1 * 64 + lane];
        a0 = fmaf(bf2f(e0 & 0xffffu), bf2f(h0 & 0xffffu), a0);
        a1 = fmaf(bf2f(e0 >> 16),     bf2f(h0 >> 16),     a1);
        a0 = fmaf(bf2f(e1 & 0xffffu), bf2f(h1 & 0xffffu), a0);
        a1 = fmaf(bf2f(e1 >> 16),     bf2f(h1 >> 16),     a1);
    }
    if (p < end) {
        int s0 = src_s[p];
        unsigned int e0 = el2[(size_t)p * 64 + lane];
        unsigned int h0 = hd2[(size_t)s0 * 64 + lane];
        a0 = fmaf(bf2f(e0 & 0xffffu), bf2f(h0 & 0xffffu), a0);
        a1 = fmaf(bf2f(e0 >> 16),     bf2f(h0 >> 16),     a1);
    }
    *(float2*)(agg + (size_t)d * 128 + 2 * lane) = make_float2(a0, a1);
}

__global__ __launch_bounds__(256)
void gn_stats(const float* __restrict__ agg, float* __restrict__ sums, int N)
{
    __shared__ float red[512];
    int f = threadIdx.x & 127;
    int sub = threadIdx.x >> 7;
    float s = 0.f, s2 = 0.f;
    for (int r = blockIdx.x * 2 + sub; r < N; r += gridDim.x * 2) {
        float v = agg[(size_t)r * 128 + f];
        s += v;
        s2 += v * v;
    }
    red[threadIdx.x] = s;
    red[256 + threadIdx.x] = s2;
    __syncthreads();
    if (sub == 0) {
        s = red[f] + red[128 + f];
        s2 = red[256 + f] + red[384 + f];
        atomicAdd(&sums[f], s);
        atomicAdd(&sums[128 + f], s2);
    }
}

__global__ void gn_finalize(const float* __restrict__ sums,
                            const float* __restrict__ gnw, const float* __restrict__ gnb,
                            const float* __restrict__ gnms, float* __restrict__ ab,
                            float invN)
{
    int f = threadIdx.x; // 128
    float mean = sums[f] * invN;
    float ex2 = sums[128 + f] * invN;
    float m2 = mean * gnms[f];
    float var = ex2 - 2.f * m2 * mean + m2 * m2;
    float rstd = 1.0f / sqrtf(var + EPS_GN);
    float a = gnw[f] * rstd;
    ab[f] = a;
    ab[128 + f] = gnb[f] - a * m2;
}

// ga = bf16(silu(a*agg+b)) elementwise
__global__ __launch_bounds__(256)
void gn_apply(const float* __restrict__ agg, const float* __restrict__ ab,
              unsigned int* __restrict__ ga, int n2 /* N*64 */)
{
    for (int i = blockIdx.x * 256 + threadIdx.x; i < n2; i += gridDim.x * 256) {
        int f = (i & 63) * 2;
        float2 v = *(const float2*)(agg + (size_t)i * 2);
        float r0 = silu_f(ab[f] * v.x + ab[128 + f]);
        float r1 = silu_f(ab[f + 1] * v.y + ab[129 + f]);
        ga[i] = f2bf(r0) | (f2bf(r1) << 16);
    }
}

// out[g] += per-graph sum of (h1[r].w2)+b2 over sorted batch, run-accumulated.
__global__ __launch_bounds__(256)
void out_reduce(const float* __restrict__ h1, const float* __restrict__ w2,
                const float* __restrict__ b2, const int* __restrict__ batch,
                float* __restrict__ out, int N)
{
    int lane = threadIdx.x & 63;
    int wid = blockIdx.x * 4 + (threadIdx.x >> 6);
    int nwaves = gridDim.x * 4;
    int chunk = (N + nwaves - 1) / nwaves;
    int r0 = wid * chunk;
    int r1 = r0 + chunk; if (r1 > N) r1 = N;
    if (r0 >= r1) return;
    float wa = w2[lane], wb = w2[64 + lane];
    float bb = b2[0];
    int cur = batch[r0];
    float acc = 0.f;
    int cnt = 0;
    for (int r = r0; r < r1; ++r) {
        int g = batch[r];
        if (g != cur) {
            float v = acc;
#pragma unroll
            for (int o = 32; o > 0; o >>= 1) v += __shfl_down(v, o);
            if (lane == 0) atomicAdd(&out[cur], v + (float)cnt * bb);
            cur = g; acc = 0.f; cnt = 0;
        }
        acc = fmaf(h1[(size_t)r * 128 + lane], wa, acc);
        acc = fmaf(h1[(size_t)r * 128 + 64 + lane], wb, acc);
        ++cnt;
    }
    float v = acc;
#pragma unroll
    for (int o = 32; o > 0; o >>= 1) v += __shfl_down(v, o);
    if (lane == 0) atomicAdd(&out[cur], v + (float)cnt * bb);
}

extern "C" void kernel_launch(void* const* d_in, const int* in_sizes, int n_in,
                              void* d_out, int out_size, void* d_ws, size_t ws_size,
                              hipStream_t stream)
{
    const int*   z         = (const int*)d_in[0];
    const int*   tag       = (const int*)d_in[1];
    const float* rel_pos   = (const float*)d_in[2];
    const float* edge_attr = (const float*)d_in[3];
    const int*   eidx      = (const int*)d_in[4];
    const int*   batch     = (const int*)d_in[5];
    const float* le1w  = (const float*)d_in[6];
    const float* le1b  = (const float*)d_in[7];
    const float* le12w = (const float*)d_in[8];
    const float* le12b = (const float*)d_in[9];
    const float* le2w  = (const float*)d_in[10];
    const float* le2b  = (const float*)d_in[11];
    const float* embw  = (const float*)d_in[12];
    const float* tembw = (const float*)d_in[13];
    const float* linw  = (const float*)d_in[14];
    const float* linb  = (const float*)d_in[15];
    const float* lin2w = (const float*)d_in[16];
    const float* lin2b = (const float*)d_in[17];
    const float* geomw = (const float*)d_in[18];
    const float* geomb = (const float*)d_in[19];
    const float* downw = (const float*)d_in[20];
    const float* downb = (const float*)d_in[21];
    const float* upw   = (const float*)d_in[22];
    const float* upb   = (const float*)d_in[23];
    const float* gnw   = (const float*)d_in[24];
    const float* gnb   = (const float*)d_in[25];
    const float* gnms  = (const float*)d_in[26];
    const float* o1w   = (const float*)d_in[27];
    const float* o1b   = (const float*)d_in[28];
    const float* o2w   = (const float*)d_in[29];
    const float* o2b   = (const float*)d_in[30];

    const int N = in_sizes[0];
    const int E = in_sizes[2] / 3;
    const int* esrc = eidx;
    const int* edst = eidx + E;

    char* ws = (char*)d_ws;
    size_t off = 0;
    unsigned short* T = (unsigned short*)(ws + off); off += (size_t)E * 128 * 2;   // hb0+t1 / el
    unsigned short* ebf = (unsigned short*)(ws + off); off += (size_t)E * 128 * 2;
    float* h   = (float*)(ws + off); off += (size_t)N * 256 * 4;
    float* agg = (float*)(ws + off); off += (size_t)N * 128 * 4;
    unsigned short* hdb = (unsigned short*)(ws + off); off += (size_t)N * 128 * 2;
    int*   cnt   = (int*)(ws + off); off += (size_t)N * 4;
    int*   src_s = (int*)(ws + off); off += (size_t)E * 4;
    unsigned short* wbuf = (unsigned short*)(ws + off); off += 442368ull * 2;
    float* stats = (float*)(ws + off); off += 256 * 4;
    float* ab    = (float*)(ws + off); off += 256 * 4;
    float* bcat  = (float*)(ws + off); off += 128;

    // aliases
    float* hb0 = (float*)T;                         // N*256 f32
    float* t1  = (float*)T + (size_t)N * 256;       // N*256 f32 (dead before layers)
    unsigned short* el = T;                         // E*128 bf16 (layers)
    int*   rank = (int*)agg;                        // E ints, dead before agg first write
    unsigned short* ga = hdb;                       // bf16 N*128, written after csr_gather
    float* h1 = agg;                                // N*128 f32, written after agg last read

    // bf16 weight buffer offsets
    unsigned short* wb_le2  = wbuf;                 // 16384
    unsigned short* wb_geom = wbuf + 16384;         // 3*16384
    unsigned short* wb_down = wbuf + 65536;         // 3*32768
    unsigned short* wb_up   = wbuf + 163840;        // 3*32768
    unsigned short* wb_lin  = wbuf + 262144;        // 65536
    unsigned short* wb_lin2 = wbuf + 327680;        // 65536
    unsigned short* wb_o1   = wbuf + 393216;        // 32768
    unsigned short* wb_cat  = wbuf + 425984;        // 8192

    const int mbE = (E + 127) / 128;
    const int mbN = (N + 127) / 128;
    dim3 blk(256);

    // weight conversions
    cvt_bf16<<<dim3(64), blk, 0, stream>>>(le2w, wb_le2, 16384);
    cvt_bf16<<<dim3(192), blk, 0, stream>>>(geomw, wb_geom, 49152);
    cvt_bf16<<<dim3(384), blk, 0, stream>>>(downw, wb_down, 98304);
    cvt_bf16<<<dim3(384), blk, 0, stream>>>(upw, wb_up, 98304);
    cvt_bf16<<<dim3(256), blk, 0, stream>>>(linw, wb_lin, 65536);
    cvt_bf16<<<dim3(256), blk, 0, stream>>>(lin2w, wb_lin2, 65536);
    cvt_bf16<<<dim3(128), blk, 0, stream>>>(o1w, wb_o1, 32768);
    build_wcat<<<dim3(32), blk, 0, stream>>>(le1w, le12w, le1b, le12b, wb_cat, bcat);

    // counting sort by dst
    hipMemsetAsync(cnt, 0, (size_t)N * sizeof(int), stream);
    edge_hist<<<dim3(3125), blk, 0, stream>>>(edst, cnt, E);
    scan_excl<<<dim3(1), dim3(1024), 0, stream>>>(cnt, N);
    edge_rank<<<dim3(3125), blk, 0, stream>>>(esrc, edst, cnt, rank, src_s, E);

    // fused edge embedding (permuted into dst-sorted order)
    edge_embed_fused<<<dim3(mbE), blk, 0, stream>>>(
        rel_pos, edge_attr, wb_cat, bcat, wb_le2, le2b, rank, ebf, E);

    // node embedding: hb0 -> t1 -> h
    node_gather<<<dim3((N + 3) / 4), blk, 0, stream>>>(z, tag, embw, tembw, hb0, N);
    mgemm<256, A_F32, ME_STORE_F32, false><<<dim3(mbN, 2), blk, 0, stream>>>(
        hb0, wb_lin, linb, t1, nullptr, N, 256, nullptr);
    mgemm<256, A_F32, ME_STORE_F32, false><<<dim3(mbN, 2), blk, 0, stream>>>(
        t1, wb_lin2, lin2b, h, nullptr, N, 256, nullptr);

    // interaction blocks
    for (int l = 0; l < 3; ++l) {
        mgemm<256, A_F32, ME_STORE_BF16, false><<<dim3(mbN, 1), blk, 0, stream>>>(
            h, wb_down + (size_t)l * 32768, downb + (size_t)l * 128,
            nullptr, hdb, N, 128, nullptr);
        mgemm<128, A_BF16, ME_STORE_BF16, true><<<dim3(mbE, 1), blk, 0, stream>>>(
            ebf, wb_geom + (size_t)l * 16384, geomb + (size_t)l * 128,
            nullptr, el, E, 128, nullptr);
        csr_gather<<<dim3((N + 3) / 4), blk, 0, stream>>>(
            (const unsigned int*)el, (const unsigned int*)hdb, src_s, cnt, agg, N);
        hipMemsetAsync(stats, 0, 256 * sizeof(float), stream);
        gn_stats<<<dim3(256), blk, 0, stream>>>(agg, stats, N);
        gn_finalize<<<dim3(1), dim3(128), 0, stream>>>(
            stats, gnw + (size_t)l * 128, gnb + (size_t)l * 128,
            gnms + (size_t)l * 128, ab, 1.0f / (float)N);
        gn_apply<<<dim3(512), blk, 0, stream>>>(agg, ab, (unsigned int*)ga, N * 64);
        mgemm<128, A_BF16, ME_RESID, true><<<dim3(mbN, 2), blk, 0, stream>>>(
            ga, wb_up + (size_t)l * 32768, upb + (size_t)l * 256,
            h, nullptr, N, 256, nullptr);
    }

    // readout
    mgemm<256, A_F32, ME_STORE_F32, false><<<dim3(mbN, 1), blk, 0, stream>>>(
        h, wb_o1, o1b, h1, nullptr, N, 128, nullptr);
    hipMemsetAsync(d_out, 0, 32 * sizeof(float), stream);
    out_reduce<<<dim3(512), blk, 0, stream>>>(h1, o2w, o2b, batch, (float*)d_out, N);
}